// Round 6
// baseline (149.394 us; speedup 1.0000x reference)
//
#include <hip/hip_runtime.h>
#include <math.h>

#define HIDDEN 256
#define NHEADS 8
#define HEAD 32
#define NTOK 2048      // tokens per batch (8*16*16)
#define NBIAS 115320   // 8 * 15 * 31 * 31
#define HTAB 14415     // 15*31*31 per-head bias entries

typedef __attribute__((ext_vector_type(8))) __bf16 bf16x8;
typedef __attribute__((ext_vector_type(4))) float f32x4;
typedef __attribute__((ext_vector_type(16))) float f32x16;
typedef __attribute__((ext_vector_type(4))) unsigned uint32x4;

static __device__ __forceinline__ f32x4 mfma16(bf16x8 a, bf16x8 b, f32x4 c) {
    return __builtin_amdgcn_mfma_f32_16x16x32_bf16(a, b, c, 0, 0, 0);
}
static __device__ __forceinline__ f32x16 mfma32(bf16x8 a, bf16x8 b, f32x16 c) {
    return __builtin_amdgcn_mfma_f32_32x32x16_bf16(a, b, c, 0, 0, 0);
}
static __device__ __forceinline__ float fexp2(float x) {
#if __has_builtin(__builtin_amdgcn_exp2f)
    return __builtin_amdgcn_exp2f(x);
#else
    return exp2f(x);
#endif
}
static __device__ __forceinline__ unsigned pkbf16(float a, float b) {
    unsigned short ua = __builtin_bit_cast(unsigned short, (__bf16)a);
    unsigned short ub = __builtin_bit_cast(unsigned short, (__bf16)b);
    return (unsigned)ua | ((unsigned)ub << 16);
}
static __device__ __forceinline__ float bflo(unsigned u) {   // low bf16 -> f32
    return __builtin_bit_cast(float, u << 16);
}
static __device__ __forceinline__ float bfhi(unsigned u) {   // high bf16 -> f32
    return __builtin_bit_cast(float, u & 0xffff0000u);
}

// ---------------- kernel 0a: x fp32 -> bf16 ----------------
__global__ void k_cvt_x(const float* __restrict__ x, __bf16* __restrict__ xb) {
    int i = (blockIdx.x * blockDim.x + threadIdx.x) * 4;
    float4 v = *(const float4*)(x + i);
    xb[i + 0] = (__bf16)v.x;
    xb[i + 1] = (__bf16)v.y;
    xb[i + 2] = (__bf16)v.z;
    xb[i + 3] = (__bf16)v.w;
}

// ---------------- kernel 0b: W fp32 -> bf16, transposed (N x K) ----------------
__global__ void k_cvt_w(const float* __restrict__ w0, const float* __restrict__ w1,
                        const float* __restrict__ w2, const float* __restrict__ w3,
                        __bf16* __restrict__ t0, __bf16* __restrict__ t1,
                        __bf16* __restrict__ t2, __bf16* __restrict__ t3) {
    int wsel = blockIdx.x >> 8;
    int i = (blockIdx.x & 255) * 256 + threadIdx.x;
    const float* w = (wsel == 0) ? w0 : (wsel == 1) ? w1 : (wsel == 2) ? w2 : w3;
    __bf16* t = (wsel == 0) ? t0 : (wsel == 1) ? t1 : (wsel == 2) ? t2 : t3;
    int n = i >> 8, k = i & 255;
    t[i] = (__bf16)w[k * 256 + n];       // t[n][k] = W[k][n]
}

// ---------------- kernel 0c: reversed bf16 bias quads, log2e folded (R4-verified) --
// bt4[head][i] = packed bf16 quad; element r of a load at J-3 yields bt[J-r].
__global__ void k_cvt_bias4(const float* __restrict__ bias, uint2* __restrict__ bt4) {
    int i = blockIdx.x * 256 + threadIdx.x;
    if (i >= NBIAS) return;
    int head = i / HTAB;
    int off = i - head * HTAB;
    int b0 = head * HTAB;
    const float L2E = 1.4426950408889634f;
    int i3 = off + 3 > HTAB - 1 ? HTAB - 1 : off + 3;
    int i2 = off + 2 > HTAB - 1 ? HTAB - 1 : off + 2;
    int i1 = off + 1 > HTAB - 1 ? HTAB - 1 : off + 1;
    float e0 = bias[b0 + i3] * L2E;
    float e1 = bias[b0 + i2] * L2E;
    float e2 = bias[b0 + i1] * L2E;
    float e3 = bias[b0 + off] * L2E;
    bt4[i] = make_uint2(pkbf16(e0, e1), pkbf16(e2, e3));
}

// ---------------- kernel 1: fused QKV projection ----------------
__global__ __launch_bounds__(256) void k_qkv(const __bf16* __restrict__ xb,
                                             const __bf16* __restrict__ wqT,
                                             const __bf16* __restrict__ wkT,
                                             const __bf16* __restrict__ wvT,
                                             __bf16* __restrict__ qb,
                                             __bf16* __restrict__ kb,
                                             __bf16* __restrict__ vb) {
    int wid = blockIdx.x * 4 + (threadIdx.x >> 6);
    int lane = threadIdx.x & 63;
    int g = wid % 12, mt = wid / 12;
    int lm = lane & 15, lg = lane >> 4, lk = lg * 8;
    int which = g >> 2;
    int nc0 = (g & 3) * 64;
    const __bf16* wT = (which == 0) ? wqT : (which == 1) ? wkT : wvT;

    f32x4 acc[4];
#pragma unroll
    for (int j = 0; j < 4; ++j) acc[j] = (f32x4){0.f, 0.f, 0.f, 0.f};

    const __bf16* arow = xb + (size_t)(mt * 16 + lm) * 256 + lk;
    const __bf16* brow = wT + (size_t)(nc0 + lm) * 256 + lk;
#pragma unroll
    for (int kk = 0; kk < 8; ++kk) {
        bf16x8 a = *(const bf16x8*)(arow + kk * 32);
#pragma unroll
        for (int j = 0; j < 4; ++j) {
            bf16x8 b = *(const bf16x8*)(brow + (size_t)j * 16 * 256 + kk * 32);
            acc[j] = mfma16(a, b, acc[j]);
        }
    }
    const float QS = 0.17677669529663687f * 1.4426950408889634f;  // 1/sqrt(32) * log2(e)
#pragma unroll
    for (int j = 0; j < 4; ++j) {
        int col = nc0 + j * 16 + lm;
        int h = col >> 5, d = col & 31;
#pragma unroll
        for (int r = 0; r < 4; ++r) {
            int row = mt * 16 + lg * 4 + r;
            int b_ = row >> 11, n = row & 2047;
            if (which == 0)      qb[((size_t)(b_ * 8 + h) * 2048 + n) * 32 + d] = (__bf16)(acc[j][r] * QS);
            else if (which == 1) kb[((size_t)(b_ * 8 + h) * 2048 + n) * 32 + d] = (__bf16)acc[j][r];
            else                 vb[((size_t)(b_ * 8 + h) * 32 + d) * 2048 + n] = (__bf16)acc[j][r]; // V^T
        }
    }
}

// ---------------- kernel 2: attention, 32x32 swapped-operand, XCD-local ----------
// XCD swizzle: blocks i with i&7==x land on XCD x; bh = (i&7)+8*(i>>9) gives each
// XCD only 4 heads -> K/V + bias working set ~1.5 MB, fits the 4 MB per-XCD L2.
__global__ __launch_bounds__(256) void k_attn(const __bf16* __restrict__ qb,
                                              const __bf16* __restrict__ kb,
                                              const __bf16* __restrict__ vb,
                                              const uint2* __restrict__ bt4all,
                                              __bf16* __restrict__ attn) {
    int i = blockIdx.x;
    int bh = (i & 7) + ((i >> 9) << 3);  // XCD-local head grouping (bijective)
    int qs = (i >> 3) & 63;              // q-strip 0..63
    int b_ = bh >> 3, h = bh & 7;
    int w = threadIdx.x >> 6;   // wave = k-quarter
    int lane = threadIdx.x & 63;
    int lq = lane & 31;
    int hf = lane >> 5;
    int q0 = qs * 32;

    const __bf16* qbase = qb + (size_t)bh * NTOK * 32;
    const __bf16* kbase = kb + (size_t)bh * NTOK * 32;
    const __bf16* vbase = vb + (size_t)bh * 32 * NTOK;
    const uint2* bt4 = bt4all + h * HTAB;

    // Q B-frags (col=lane&31=q, k=8*hf+j), d-chunks 0 and 1 — loop invariant
    bf16x8 qf0 = *(const bf16x8*)(qbase + (size_t)(q0 + lq) * 32 + hf * 8);
    bf16x8 qf1 = *(const bf16x8*)(qbase + (size_t)(q0 + lq) * 32 + 16 + hf * 8);

    int qg = q0 + lq;
    // loop-invariant part of bias index J (includes -4hf of the k-token code)
    int qidx4 = (qg >> 8) * 961 + ((qg >> 4) & 15) * 31 + (qg & 15) + 7207 - 4 * hf;

    f32x16 Oacc, Lacc;
#pragma unroll
    for (int j = 0; j < 16; ++j) { Oacc[j] = 0.f; Lacc[j] = 0.f; }

    bf16x8 ones;
#pragma unroll
    for (int j = 0; j < 8; ++j) ones[j] = (__bf16)1.0f;

    // ---- pipeline registers: bias quads + K frags for the CURRENT iter ----
    uint2 cb0, cb1, cb2, cb3;
    bf16x8 ck0, ck1;
    {
        int t0 = w * 512;
        int c00 = (t0 >> 8) * 961 + ((t0 >> 4) & 15) * 31;
        int jb = qidx4 - c00;
        cb0 = bt4[jb - 3];
        cb1 = bt4[jb - 11];
        cb2 = bt4[jb - 34];
        cb3 = bt4[jb - 42];
        const __bf16* kp = kbase + (size_t)(t0 + lq) * 32 + hf * 8;
        ck0 = *(const bf16x8*)(kp);
        ck1 = *(const bf16x8*)(kp + 16);
    }

#pragma unroll
    for (int it = 0; it < 16; ++it) {
        int t0 = w * 512 + it * 32;

        // ---- prefetch iter+1 (issued before any use of current loads) ----
        uint2 nb0, nb1, nb2, nb3;
        bf16x8 nk0, nk1;
        if (it < 15) {
            int t1 = t0 + 32;
            int c01 = (t1 >> 8) * 961 + ((t1 >> 4) & 15) * 31;
            int jb1 = qidx4 - c01;
            nb0 = bt4[jb1 - 3];
            nb1 = bt4[jb1 - 11];
            nb2 = bt4[jb1 - 34];
            nb3 = bt4[jb1 - 42];
            const __bf16* kp1 = kbase + (size_t)(t1 + lq) * 32 + hf * 8;
            nk0 = *(const bf16x8*)(kp1);
            nk1 = *(const bf16x8*)(kp1 + 16);
        }

        // ---- V^T loads for THIS iter ----
        // element j <- token t0 + 4hf + 8*(j>>2) + (j&3)  (matches P's in-lane order)
        const __bf16* vp = vbase + (size_t)lq * NTOK + t0 + 4 * hf;
        uint2 va = *(const uint2*)(vp);
        uint2 vbq = *(const uint2*)(vp + 8);
        uint2 vc = *(const uint2*)(vp + 16);
        uint2 vd = *(const uint2*)(vp + 24);
        uint32x4 vw0 = {va.x, va.y, vbq.x, vbq.y};
        uint32x4 vw1 = {vc.x, vc.y, vd.x, vd.y};
        bf16x8 vf0 = __builtin_bit_cast(bf16x8, vw0);
        bf16x8 vf1 = __builtin_bit_cast(bf16x8, vw1);

        // ---- S = bias-init (bf16 unpack, R4-verified mapping), then QK^T ----
        f32x16 S;
        S[0]  = bflo(cb0.x); S[1]  = bfhi(cb0.x); S[2]  = bflo(cb0.y); S[3]  = bfhi(cb0.y);
        S[4]  = bflo(cb1.x); S[5]  = bfhi(cb1.x); S[6]  = bflo(cb1.y); S[7]  = bfhi(cb1.y);
        S[8]  = bflo(cb2.x); S[9]  = bfhi(cb2.x); S[10] = bflo(cb2.y); S[11] = bfhi(cb2.y);
        S[12] = bflo(cb3.x); S[13] = bfhi(cb3.x); S[14] = bflo(cb3.y); S[15] = bfhi(cb3.y);
        S = mfma32(ck0, qf0, S);
        S = mfma32(ck1, qf1, S);

        // ---- P = exp2(S) -> packed bf16 pairs ----
        unsigned W0 = pkbf16(fexp2(S[0]),  fexp2(S[1]));
        unsigned W1 = pkbf16(fexp2(S[2]),  fexp2(S[3]));
        unsigned W2 = pkbf16(fexp2(S[4]),  fexp2(S[5]));
        unsigned W3 = pkbf16(fexp2(S[6]),  fexp2(S[7]));
        unsigned W4 = pkbf16(fexp2(S[8]),  fexp2(S[9]));
        unsigned W5 = pkbf16(fexp2(S[10]), fexp2(S[11]));
        unsigned W6 = pkbf16(fexp2(S[12]), fexp2(S[13]));
        unsigned W7 = pkbf16(fexp2(S[14]), fexp2(S[15]));
        uint32x4 pw0 = {W0, W1, W2, W3};
        uint32x4 pw1 = {W4, W5, W6, W7};
        bf16x8 pf0 = __builtin_bit_cast(bf16x8, pw0);
        bf16x8 pf1 = __builtin_bit_cast(bf16x8, pw1);

        Oacc = mfma32(vf0, pf0, Oacc);   // O^T[d][q] += V^T . P (common token perm)
        Oacc = mfma32(vf1, pf1, Oacc);
        Lacc = mfma32(ones, pf0, Lacc);  // every reg = lsum[q] partial
        Lacc = mfma32(ones, pf1, Lacc);

        // ---- rotate pipeline ----
        if (it < 15) {
            cb0 = nb0; cb1 = nb1; cb2 = nb2; cb3 = nb3;
            ck0 = nk0; ck1 = nk1;
        }
    }

    // ---- combine 4 k-partials via LDS ----
    __shared__ float part[4][64][17];   // 16 O + 1 lsum; stride 17 (odd -> bank-friendly)
#pragma unroll
    for (int j = 0; j < 4; ++j) {
        float4 t;
        t.x = Oacc[4 * j]; t.y = Oacc[4 * j + 1]; t.z = Oacc[4 * j + 2]; t.w = Oacc[4 * j + 3];
        *(float4*)&part[w][lane][4 * j] = t;
    }
    part[w][lane][16] = Lacc[0];
    __syncthreads();

    float4 o = {0.f, 0.f, 0.f, 0.f};
    float ls = 0.f;
#pragma unroll
    for (int sw = 0; sw < 4; ++sw) {
        float4 t = *(const float4*)&part[sw][lane][4 * w];
        o.x += t.x; o.y += t.y; o.z += t.z; o.w += t.w;
        ls += part[sw][lane][16];
    }
    float inv = 1.0f / ls;
    // wave w keeps regs 4w..4w+3 -> d = r + 8w + 4hf
    unsigned lo = pkbf16(o.x * inv, o.y * inv);
    unsigned hi = pkbf16(o.z * inv, o.w * inv);
    size_t base = ((size_t)b_ * NTOK + q0 + lq) * 256 + h * 32 + 8 * w + 4 * hf;
    *(uint2*)(attn + base) = make_uint2(lo, hi);
}

// ---------------- kernel 3: output projection -> fp32 ----------------
__global__ __launch_bounds__(256) void k_out(const __bf16* __restrict__ attn,
                                             const __bf16* __restrict__ woT,
                                             float* __restrict__ out) {
    int wid = blockIdx.x * 4 + (threadIdx.x >> 6);
    int lane = threadIdx.x & 63;
    int ng = wid & 3, mt = wid >> 2;
    int lm = lane & 15, lg = lane >> 4, lk = lg * 8;
    int nc0 = ng * 64;

    f32x4 acc[4];
#pragma unroll
    for (int j = 0; j < 4; ++j) acc[j] = (f32x4){0.f, 0.f, 0.f, 0.f};

    const __bf16* arow = attn + (size_t)(mt * 16 + lm) * 256 + lk;
    const __bf16* brow = woT + (size_t)(nc0 + lm) * 256 + lk;
#pragma unroll
    for (int kk = 0; kk < 8; ++kk) {
        bf16x8 a = *(const bf16x8*)(arow + kk * 32);
#pragma unroll
        for (int j = 0; j < 4; ++j) {
            bf16x8 b = *(const bf16x8*)(brow + (size_t)j * 16 * 256 + kk * 32);
            acc[j] = mfma16(a, b, acc[j]);
        }
    }
#pragma unroll
    for (int j = 0; j < 4; ++j) {
        int col = nc0 + j * 16 + lm;
#pragma unroll
        for (int r = 0; r < 4; ++r) {
            int row = mt * 16 + lg * 4 + r;
            out[(size_t)row * 256 + col] = acc[j][r];
        }
    }
}

extern "C" void kernel_launch(void* const* d_in, const int* in_sizes, int n_in,
                              void* d_out, int out_size, void* d_ws, size_t ws_size,
                              hipStream_t stream) {
    const float* x    = (const float*)d_in[0];
    const float* Wq   = (const float*)d_in[1];
    const float* Wk   = (const float*)d_in[2];
    const float* Wv   = (const float*)d_in[3];
    const float* Wo   = (const float*)d_in[4];
    const float* bias = (const float*)d_in[5];
    float* out = (float*)d_out;

    __bf16* ws  = (__bf16*)d_ws;
    __bf16* xb  = ws;                       // 2,097,152 bf16 (reused as att)
    __bf16* wqT = xb  + 2097152;
    __bf16* wkT = wqT + 65536;
    __bf16* wvT = wkT + 65536;
    __bf16* woT = wvT + 65536;
    __bf16* qb  = woT + 65536;              // (b,h,n,32)
    __bf16* kb  = qb  + 2097152;            // (b,h,n,32)
    __bf16* vb  = kb  + 2097152;            // (b,h,32,n)  V^T
    uint2*  bt4 = (uint2*)(vb + 2097152);   // 115320 x 8B packed bf16 bias quads
    __bf16* att = xb;                       // alias: xb dead after k_qkv

    k_cvt_x<<<2048, 256, 0, stream>>>(x, xb);
    k_cvt_w<<<1024, 256, 0, stream>>>(Wq, Wk, Wv, Wo, wqT, wkT, wvT, woT);
    k_cvt_bias4<<<(NBIAS + 255) / 256, 256, 0, stream>>>(bias, bt4);
    k_qkv<<<1536, 256, 0, stream>>>(xb, wqT, wkT, wvT, qb, kb, vb);
    k_attn<<<2048, 256, 0, stream>>>(qb, kb, vb, bt4, att);
    k_out<<<512, 256, 0, stream>>>(att, woT, out);
}

// Round 7
// 101.114 us; speedup vs baseline: 1.4775x; 1.4775x over previous
//
#include <hip/hip_runtime.h>
#include <math.h>

#define HIDDEN 256
#define NHEADS 8
#define HEAD 32
#define NTOK 2048      // tokens per batch (8*16*16)
#define NBIAS 115320   // 8 * 15 * 31 * 31
#define HTAB 14415     // 15*31*31 per-head bias entries

typedef __attribute__((ext_vector_type(8))) __bf16 bf16x8;
typedef __attribute__((ext_vector_type(4))) float f32x4;
typedef __attribute__((ext_vector_type(16))) float f32x16;
typedef __attribute__((ext_vector_type(4))) unsigned uint32x4;

static __device__ __forceinline__ f32x4 mfma16(bf16x8 a, bf16x8 b, f32x4 c) {
    return __builtin_amdgcn_mfma_f32_16x16x32_bf16(a, b, c, 0, 0, 0);
}
static __device__ __forceinline__ f32x16 mfma32(bf16x8 a, bf16x8 b, f32x16 c) {
    return __builtin_amdgcn_mfma_f32_32x32x16_bf16(a, b, c, 0, 0, 0);
}
static __device__ __forceinline__ float fexp2(float x) {
#if __has_builtin(__builtin_amdgcn_exp2f)
    return __builtin_amdgcn_exp2f(x);
#else
    return exp2f(x);
#endif
}
static __device__ __forceinline__ unsigned pkbf16(float a, float b) {
    unsigned short ua = __builtin_bit_cast(unsigned short, (__bf16)a);
    unsigned short ub = __builtin_bit_cast(unsigned short, (__bf16)b);
    return (unsigned)ua | ((unsigned)ub << 16);
}
static __device__ __forceinline__ float bflo(unsigned u) {   // low bf16 -> f32
    return __builtin_bit_cast(float, u << 16);
}
static __device__ __forceinline__ float bfhi(unsigned u) {   // high bf16 -> f32
    return __builtin_bit_cast(float, u & 0xffff0000u);
}

// ---------------- kernel 0a: x fp32 -> bf16 ----------------
__global__ void k_cvt_x(const float* __restrict__ x, __bf16* __restrict__ xb) {
    int i = (blockIdx.x * blockDim.x + threadIdx.x) * 4;
    float4 v = *(const float4*)(x + i);
    xb[i + 0] = (__bf16)v.x;
    xb[i + 1] = (__bf16)v.y;
    xb[i + 2] = (__bf16)v.z;
    xb[i + 3] = (__bf16)v.w;
}

// ---------------- kernel 0b: W fp32 -> bf16, transposed (N x K) ----------------
__global__ void k_cvt_w(const float* __restrict__ w0, const float* __restrict__ w1,
                        const float* __restrict__ w2, const float* __restrict__ w3,
                        __bf16* __restrict__ t0, __bf16* __restrict__ t1,
                        __bf16* __restrict__ t2, __bf16* __restrict__ t3) {
    int wsel = blockIdx.x >> 8;
    int i = (blockIdx.x & 255) * 256 + threadIdx.x;
    const float* w = (wsel == 0) ? w0 : (wsel == 1) ? w1 : (wsel == 2) ? w2 : w3;
    __bf16* t = (wsel == 0) ? t0 : (wsel == 1) ? t1 : (wsel == 2) ? t2 : t3;
    int n = i >> 8, k = i & 255;
    t[i] = (__bf16)w[k * 256 + n];       // t[n][k] = W[k][n]
}

// ---------------- kernel 0c: reversed bf16 bias quads, log2e folded (R4-verified) --
// bt4[head][i] = packed bf16 quad; element r of a load at J-3 yields bt[J-r].
__global__ void k_cvt_bias4(const float* __restrict__ bias, uint2* __restrict__ bt4) {
    int i = blockIdx.x * 256 + threadIdx.x;
    if (i >= NBIAS) return;
    int head = i / HTAB;
    int off = i - head * HTAB;
    int b0 = head * HTAB;
    const float L2E = 1.4426950408889634f;
    int i3 = off + 3 > HTAB - 1 ? HTAB - 1 : off + 3;
    int i2 = off + 2 > HTAB - 1 ? HTAB - 1 : off + 2;
    int i1 = off + 1 > HTAB - 1 ? HTAB - 1 : off + 1;
    float e0 = bias[b0 + i3] * L2E;
    float e1 = bias[b0 + i2] * L2E;
    float e2 = bias[b0 + i1] * L2E;
    float e3 = bias[b0 + off] * L2E;
    bt4[i] = make_uint2(pkbf16(e0, e1), pkbf16(e2, e3));
}

// ---------------- kernel 1: fused QKV projection ----------------
// K and V are written in FRAGMENT-MAJOR tiled layouts so k_attn's loads are
// fully coalesced (unit index = tile_base + lane):
//   K frag (t,j,hf,lq) 16B unit at t*128 + j*64 + hf*32 + lq
//     holds K[32t+lq][8hf+16j+e], e=0..7
//   V frag (t,g,hf,d)  8B unit at t*256 + g*64 + hf*32 + d
//     holds V[32t+8g+4hf+s][d], s=0..3
__global__ __launch_bounds__(256) void k_qkv(const __bf16* __restrict__ xb,
                                             const __bf16* __restrict__ wqT,
                                             const __bf16* __restrict__ wkT,
                                             const __bf16* __restrict__ wvT,
                                             __bf16* __restrict__ qb,
                                             __bf16* __restrict__ kb,
                                             __bf16* __restrict__ vb) {
    int wid = blockIdx.x * 4 + (threadIdx.x >> 6);
    int lane = threadIdx.x & 63;
    int g = wid % 12, mt = wid / 12;
    int lm = lane & 15, lg = lane >> 4, lk = lg * 8;
    int which = g >> 2;
    int nc0 = (g & 3) * 64;
    const __bf16* wT = (which == 0) ? wqT : (which == 1) ? wkT : wvT;

    f32x4 acc[4];
#pragma unroll
    for (int j = 0; j < 4; ++j) acc[j] = (f32x4){0.f, 0.f, 0.f, 0.f};

    const __bf16* arow = xb + (size_t)(mt * 16 + lm) * 256 + lk;
    const __bf16* brow = wT + (size_t)(nc0 + lm) * 256 + lk;
#pragma unroll
    for (int kk = 0; kk < 8; ++kk) {
        bf16x8 a = *(const bf16x8*)(arow + kk * 32);
#pragma unroll
        for (int j = 0; j < 4; ++j) {
            bf16x8 b = *(const bf16x8*)(brow + (size_t)j * 16 * 256 + kk * 32);
            acc[j] = mfma16(a, b, acc[j]);
        }
    }
    const float QS = 0.17677669529663687f * 1.4426950408889634f;  // 1/sqrt(32) * log2(e)
#pragma unroll
    for (int j = 0; j < 4; ++j) {
        int col = nc0 + j * 16 + lm;
        int h = col >> 5, d = col & 31;
#pragma unroll
        for (int r = 0; r < 4; ++r) {
            int row = mt * 16 + lg * 4 + r;
            int b_ = row >> 11, n = row & 2047;
            size_t bh = (size_t)(b_ * 8 + h) * 65536;   // 2048*32 per (b,h)
            if (which == 0) {
                qb[bh + (size_t)n * 32 + d] = (__bf16)(acc[j][r] * QS);
            } else if (which == 1) {
                size_t idx = ((size_t)(n >> 5) * 128 + (d >> 4) * 64 + ((d >> 3) & 1) * 32 + (n & 31)) * 8 + (d & 7);
                kb[bh + idx] = (__bf16)acc[j][r];
            } else {
                size_t idx = ((size_t)(n >> 5) * 256 + ((n >> 3) & 3) * 64 + ((n >> 2) & 1) * 32 + d) * 4 + (n & 3);
                vb[bh + idx] = (__bf16)acc[j][r];
            }
        }
    }
}

// ---------------- kernel 2: attention, 32x32 swapped-operand, coalesced frags ----
// XCD swizzle: bh = (i&7)+8*(i>>9) keeps each XCD on 4 heads (L2-resident K/V).
// All K/V loads are now contiguous 1KB / 512B per wave-instruction.
__global__ __launch_bounds__(256) void k_attn(const __bf16* __restrict__ qb,
                                              const __bf16* __restrict__ kb,
                                              const __bf16* __restrict__ vb,
                                              const uint2* __restrict__ bt4all,
                                              __bf16* __restrict__ attn) {
    int i = blockIdx.x;
    int bh = (i & 7) + ((i >> 9) << 3);  // XCD-local head grouping (bijective)
    int qs = (i >> 3) & 63;              // q-strip 0..63
    int b_ = bh >> 3, h = bh & 7;
    int w = threadIdx.x >> 6;   // wave = k-quarter
    int lane = threadIdx.x & 63;
    int lq = lane & 31;
    int hf = lane >> 5;
    int q0 = qs * 32;

    const __bf16* qbase = qb + (size_t)bh * NTOK * 32;
    const __bf16* kbase = kb + (size_t)bh * NTOK * 32;
    const __bf16* vbase = vb + (size_t)bh * NTOK * 32;
    const uint2* bt4 = bt4all + h * HTAB;

    // Q B-frags (col=lane&31=q, k=8*hf+j), d-chunks 0 and 1 — loop invariant
    bf16x8 qf0 = *(const bf16x8*)(qbase + (size_t)(q0 + lq) * 32 + hf * 8);
    bf16x8 qf1 = *(const bf16x8*)(qbase + (size_t)(q0 + lq) * 32 + 16 + hf * 8);

    int qg = q0 + lq;
    // loop-invariant part of bias index J (includes -4hf of the k-token code)
    int qidx4 = (qg >> 8) * 961 + ((qg >> 4) & 15) * 31 + (qg & 15) + 7207 - 4 * hf;

    f32x16 Oacc, Lacc;
#pragma unroll
    for (int j = 0; j < 16; ++j) { Oacc[j] = 0.f; Lacc[j] = 0.f; }

    bf16x8 ones;
#pragma unroll
    for (int j = 0; j < 8; ++j) ones[j] = (__bf16)1.0f;

    // ---- pipeline registers: bias quads + K frags for the CURRENT iter ----
    uint2 cb0, cb1, cb2, cb3;
    bf16x8 ck0, ck1;
    {
        int t0 = w * 512;
        int tt = t0 >> 5;
        int c00 = (t0 >> 8) * 961 + ((t0 >> 4) & 15) * 31;
        int jb = qidx4 - c00;
        cb0 = bt4[jb - 3];
        cb1 = bt4[jb - 11];
        cb2 = bt4[jb - 34];
        cb3 = bt4[jb - 42];
        const __bf16* kt = kbase + ((size_t)tt * 128 + lane) * 8;
        ck0 = *(const bf16x8*)(kt);
        ck1 = *(const bf16x8*)(kt + 512);   // j=1: +64 units * 8
    }

#pragma unroll
    for (int it = 0; it < 16; ++it) {
        int t0 = w * 512 + it * 32;
        int tt = t0 >> 5;

        // ---- prefetch iter+1 (issued before any use of current loads) ----
        uint2 nb0, nb1, nb2, nb3;
        bf16x8 nk0, nk1;
        if (it < 15) {
            int t1 = t0 + 32;
            int c01 = (t1 >> 8) * 961 + ((t1 >> 4) & 15) * 31;
            int jb1 = qidx4 - c01;
            nb0 = bt4[jb1 - 3];
            nb1 = bt4[jb1 - 11];
            nb2 = bt4[jb1 - 34];
            nb3 = bt4[jb1 - 42];
            const __bf16* kt1 = kbase + ((size_t)(tt + 1) * 128 + lane) * 8;
            nk0 = *(const bf16x8*)(kt1);
            nk1 = *(const bf16x8*)(kt1 + 512);
        }

        // ---- V frags for THIS iter (contiguous: unit = tt*256 + g*64 + lane) ----
        const __bf16* vt = vbase + ((size_t)tt * 256 + lane) * 4;
        uint2 va  = *(const uint2*)(vt);          // g=0
        uint2 vbq = *(const uint2*)(vt + 256);    // g=1
        uint2 vc  = *(const uint2*)(vt + 512);    // g=2
        uint2 vd  = *(const uint2*)(vt + 768);    // g=3
        uint32x4 vw0 = {va.x, va.y, vbq.x, vbq.y};
        uint32x4 vw1 = {vc.x, vc.y, vd.x, vd.y};
        bf16x8 vf0 = __builtin_bit_cast(bf16x8, vw0);
        bf16x8 vf1 = __builtin_bit_cast(bf16x8, vw1);

        // ---- S = bias-init (bf16 unpack, R4-verified mapping), then QK^T ----
        f32x16 S;
        S[0]  = bflo(cb0.x); S[1]  = bfhi(cb0.x); S[2]  = bflo(cb0.y); S[3]  = bfhi(cb0.y);
        S[4]  = bflo(cb1.x); S[5]  = bfhi(cb1.x); S[6]  = bflo(cb1.y); S[7]  = bfhi(cb1.y);
        S[8]  = bflo(cb2.x); S[9]  = bfhi(cb2.x); S[10] = bflo(cb2.y); S[11] = bfhi(cb2.y);
        S[12] = bflo(cb3.x); S[13] = bfhi(cb3.x); S[14] = bflo(cb3.y); S[15] = bfhi(cb3.y);
        S = mfma32(ck0, qf0, S);
        S = mfma32(ck1, qf1, S);

        // ---- P = exp2(S) -> packed bf16 pairs ----
        unsigned W0 = pkbf16(fexp2(S[0]),  fexp2(S[1]));
        unsigned W1 = pkbf16(fexp2(S[2]),  fexp2(S[3]));
        unsigned W2 = pkbf16(fexp2(S[4]),  fexp2(S[5]));
        unsigned W3 = pkbf16(fexp2(S[6]),  fexp2(S[7]));
        unsigned W4 = pkbf16(fexp2(S[8]),  fexp2(S[9]));
        unsigned W5 = pkbf16(fexp2(S[10]), fexp2(S[11]));
        unsigned W6 = pkbf16(fexp2(S[12]), fexp2(S[13]));
        unsigned W7 = pkbf16(fexp2(S[14]), fexp2(S[15]));
        uint32x4 pw0 = {W0, W1, W2, W3};
        uint32x4 pw1 = {W4, W5, W6, W7};
        bf16x8 pf0 = __builtin_bit_cast(bf16x8, pw0);
        bf16x8 pf1 = __builtin_bit_cast(bf16x8, pw1);

        Oacc = mfma32(vf0, pf0, Oacc);   // O^T[d][q] += V^T . P (common token perm)
        Oacc = mfma32(vf1, pf1, Oacc);
        Lacc = mfma32(ones, pf0, Lacc);  // every reg = lsum[q] partial
        Lacc = mfma32(ones, pf1, Lacc);

        // ---- rotate pipeline ----
        if (it < 15) {
            cb0 = nb0; cb1 = nb1; cb2 = nb2; cb3 = nb3;
            ck0 = nk0; ck1 = nk1;
        }
    }

    // ---- combine 4 k-partials via LDS ----
    __shared__ float part[4][64][17];   // 16 O + 1 lsum; stride 17 (odd -> bank-friendly)
#pragma unroll
    for (int j = 0; j < 4; ++j) {
        float4 t;
        t.x = Oacc[4 * j]; t.y = Oacc[4 * j + 1]; t.z = Oacc[4 * j + 2]; t.w = Oacc[4 * j + 3];
        *(float4*)&part[w][lane][4 * j] = t;
    }
    part[w][lane][16] = Lacc[0];
    __syncthreads();

    float4 o = {0.f, 0.f, 0.f, 0.f};
    float ls = 0.f;
#pragma unroll
    for (int sw = 0; sw < 4; ++sw) {
        float4 t = *(const float4*)&part[sw][lane][4 * w];
        o.x += t.x; o.y += t.y; o.z += t.z; o.w += t.w;
        ls += part[sw][lane][16];
    }
    float inv = 1.0f / ls;
    // wave w keeps regs 4w..4w+3 -> d = r + 8w + 4hf
    unsigned lo = pkbf16(o.x * inv, o.y * inv);
    unsigned hi = pkbf16(o.z * inv, o.w * inv);
    size_t base = ((size_t)b_ * NTOK + q0 + lq) * 256 + h * 32 + 8 * w + 4 * hf;
    *(uint2*)(attn + base) = make_uint2(lo, hi);
}

// ---------------- kernel 3: output projection -> fp32 ----------------
__global__ __launch_bounds__(256) void k_out(const __bf16* __restrict__ attn,
                                             const __bf16* __restrict__ woT,
                                             float* __restrict__ out) {
    int wid = blockIdx.x * 4 + (threadIdx.x >> 6);
    int lane = threadIdx.x & 63;
    int ng = wid & 3, mt = wid >> 2;
    int lm = lane & 15, lg = lane >> 4, lk = lg * 8;
    int nc0 = ng * 64;

    f32x4 acc[4];
#pragma unroll
    for (int j = 0; j < 4; ++j) acc[j] = (f32x4){0.f, 0.f, 0.f, 0.f};

    const __bf16* arow = attn + (size_t)(mt * 16 + lm) * 256 + lk;
    const __bf16* brow = woT + (size_t)(nc0 + lm) * 256 + lk;
#pragma unroll
    for (int kk = 0; kk < 8; ++kk) {
        bf16x8 a = *(const bf16x8*)(arow + kk * 32);
#pragma unroll
        for (int j = 0; j < 4; ++j) {
            bf16x8 b = *(const bf16x8*)(brow + (size_t)j * 16 * 256 + kk * 32);
            acc[j] = mfma16(a, b, acc[j]);
        }
    }
#pragma unroll
    for (int j = 0; j < 4; ++j) {
        int col = nc0 + j * 16 + lm;
#pragma unroll
        for (int r = 0; r < 4; ++r) {
            int row = mt * 16 + lg * 4 + r;
            out[(size_t)row * 256 + col] = acc[j][r];
        }
    }
}

extern "C" void kernel_launch(void* const* d_in, const int* in_sizes, int n_in,
                              void* d_out, int out_size, void* d_ws, size_t ws_size,
                              hipStream_t stream) {
    const float* x    = (const float*)d_in[0];
    const float* Wq   = (const float*)d_in[1];
    const float* Wk   = (const float*)d_in[2];
    const float* Wv   = (const float*)d_in[3];
    const float* Wo   = (const float*)d_in[4];
    const float* bias = (const float*)d_in[5];
    float* out = (float*)d_out;

    __bf16* ws  = (__bf16*)d_ws;
    __bf16* xb  = ws;                       // 2,097,152 bf16 (reused as att)
    __bf16* wqT = xb  + 2097152;
    __bf16* wkT = wqT + 65536;
    __bf16* wvT = wkT + 65536;
    __bf16* woT = wvT + 65536;
    __bf16* qb  = woT + 65536;              // (b,h,n,32)
    __bf16* kb  = qb  + 2097152;            // (b,h) fragment-major K tiles
    __bf16* vb  = kb  + 2097152;            // (b,h) fragment-major V tiles
    uint2*  bt4 = (uint2*)(vb + 2097152);   // 115320 x 8B packed bf16 bias quads
    __bf16* att = xb;                       // alias: xb dead after k_qkv

    k_cvt_x<<<2048, 256, 0, stream>>>(x, xb);
    k_cvt_w<<<1024, 256, 0, stream>>>(Wq, Wk, Wv, Wo, wqT, wkT, wvT, woT);
    k_cvt_bias4<<<(NBIAS + 255) / 256, 256, 0, stream>>>(bias, bt4);
    k_qkv<<<1536, 256, 0, stream>>>(xb, wqT, wkT, wvT, qb, kb, vb);
    k_attn<<<2048, 256, 0, stream>>>(qb, kb, vb, bt4, att);
    k_out<<<512, 256, 0, stream>>>(att, woT, out);
}

// Round 8
// 90.915 us; speedup vs baseline: 1.6432x; 1.1122x over previous
//
#include <hip/hip_runtime.h>
#include <math.h>

#define HIDDEN 256
#define NHEADS 8
#define HEAD 32
#define NTOK 2048      // tokens per batch (8*16*16)
#define NBIAS 115320   // 8 * 15 * 31 * 31
#define HTAB 14415     // 15*31*31 per-head bias entries

typedef __attribute__((ext_vector_type(8))) __bf16 bf16x8;
typedef __attribute__((ext_vector_type(4))) float f32x4;
typedef __attribute__((ext_vector_type(16))) float f32x16;
typedef __attribute__((ext_vector_type(4))) unsigned uint32x4;

static __device__ __forceinline__ f32x4 mfma16(bf16x8 a, bf16x8 b, f32x4 c) {
    return __builtin_amdgcn_mfma_f32_16x16x32_bf16(a, b, c, 0, 0, 0);
}
static __device__ __forceinline__ f32x16 mfma32(bf16x8 a, bf16x8 b, f32x16 c) {
    return __builtin_amdgcn_mfma_f32_32x32x16_bf16(a, b, c, 0, 0, 0);
}
static __device__ __forceinline__ float fexp2(float x) {
#if __has_builtin(__builtin_amdgcn_exp2f)
    return __builtin_amdgcn_exp2f(x);
#else
    return exp2f(x);
#endif
}
static __device__ __forceinline__ unsigned pkbf16(float a, float b) {
    unsigned short ua = __builtin_bit_cast(unsigned short, (__bf16)a);
    unsigned short ub = __builtin_bit_cast(unsigned short, (__bf16)b);
    return (unsigned)ua | ((unsigned)ub << 16);
}

// ---------------- kernel 0a: x fp32 -> bf16 ----------------
__global__ void k_cvt_x(const float* __restrict__ x, __bf16* __restrict__ xb) {
    int i = (blockIdx.x * blockDim.x + threadIdx.x) * 4;
    float4 v = *(const float4*)(x + i);
    xb[i + 0] = (__bf16)v.x;
    xb[i + 1] = (__bf16)v.y;
    xb[i + 2] = (__bf16)v.z;
    xb[i + 3] = (__bf16)v.w;
}

// ---------------- kernel 0b: W fp32 -> bf16, transposed (N x K) ----------------
__global__ void k_cvt_w(const float* __restrict__ w0, const float* __restrict__ w1,
                        const float* __restrict__ w2, const float* __restrict__ w3,
                        __bf16* __restrict__ t0, __bf16* __restrict__ t1,
                        __bf16* __restrict__ t2, __bf16* __restrict__ t3) {
    int wsel = blockIdx.x >> 8;
    int i = (blockIdx.x & 255) * 256 + threadIdx.x;
    const float* w = (wsel == 0) ? w0 : (wsel == 1) ? w1 : (wsel == 2) ? w2 : w3;
    __bf16* t = (wsel == 0) ? t0 : (wsel == 1) ? t1 : (wsel == 2) ? t2 : t3;
    int n = i >> 8, k = i & 255;
    t[i] = (__bf16)w[k * 256 + n];       // t[n][k] = W[k][n]
}

// ---------------- kernel 0c: reversed f32 bias quads, log2e folded (R5-verified) --
// btq[head][i] = float4 {bt[i+3], bt[i+2], bt[i+1], bt[i]} * log2e:
// a 16B load at J-3 yields element r = bt[J-r], landing directly in MFMA C-init.
__global__ void k_cvt_biasq(const float* __restrict__ bias, float4* __restrict__ btq) {
    int i = blockIdx.x * 256 + threadIdx.x;
    if (i >= NBIAS) return;
    int head = i / HTAB;
    int off = i - head * HTAB;
    int b0 = head * HTAB;
    const float L2E = 1.4426950408889634f;
    int i3 = off + 3 > HTAB - 1 ? HTAB - 1 : off + 3;
    int i2 = off + 2 > HTAB - 1 ? HTAB - 1 : off + 2;
    int i1 = off + 1 > HTAB - 1 ? HTAB - 1 : off + 1;
    btq[i] = make_float4(bias[b0 + i3] * L2E, bias[b0 + i2] * L2E,
                         bias[b0 + i1] * L2E, bias[b0 + off] * L2E);
}

// ---------------- kernel 1: fused QKV projection, 64x64 tile per wave ----------
// 1536 waves: mt in [0,128) x ng in [0,12). 4 A-frags x 4 B-frags -> 16 MFMAs
// per 8 loads (2.4x fewer bytes/MFMA than 16x64).
// K and V written in FRAGMENT-MAJOR tiled layouts (R7-verified):
//   K frag 16B unit at t*128 + j*64 + hf*32 + lq : K[32t+lq][8hf+16j+e]
//   V frag  8B unit at t*256 + g*64 + hf*32 + d  : V[32t+8g+4hf+s][d]
__global__ __launch_bounds__(256) void k_qkv(const __bf16* __restrict__ xb,
                                             const __bf16* __restrict__ wqT,
                                             const __bf16* __restrict__ wkT,
                                             const __bf16* __restrict__ wvT,
                                             __bf16* __restrict__ qb,
                                             __bf16* __restrict__ kb,
                                             __bf16* __restrict__ vb) {
    int wid = blockIdx.x * 4 + (threadIdx.x >> 6);   // 0..1535
    int lane = threadIdx.x & 63;
    int ng = wid % 12, mt = wid / 12;                // mt 0..127
    int lm = lane & 15, lg = lane >> 4, lk = lg * 8;
    int which = ng >> 2;
    int nc0 = (ng & 3) * 64;
    const __bf16* wT = (which == 0) ? wqT : (which == 1) ? wkT : wvT;

    f32x4 acc[4][4];
#pragma unroll
    for (int m = 0; m < 4; ++m)
#pragma unroll
        for (int n = 0; n < 4; ++n) acc[m][n] = (f32x4){0.f, 0.f, 0.f, 0.f};

    const __bf16* arow = xb + (size_t)(mt * 64 + lm) * 256 + lk;
    const __bf16* brow = wT + (size_t)(nc0 + lm) * 256 + lk;
#pragma unroll
    for (int kk = 0; kk < 8; ++kk) {
        bf16x8 a[4], b[4];
#pragma unroll
        for (int m = 0; m < 4; ++m) a[m] = *(const bf16x8*)(arow + (size_t)m * 16 * 256 + kk * 32);
#pragma unroll
        for (int n = 0; n < 4; ++n) b[n] = *(const bf16x8*)(brow + (size_t)n * 16 * 256 + kk * 32);
#pragma unroll
        for (int m = 0; m < 4; ++m)
#pragma unroll
            for (int n = 0; n < 4; ++n) acc[m][n] = mfma16(a[m], b[n], acc[m][n]);
    }
    const float QS = 0.17677669529663687f * 1.4426950408889634f;  // 1/sqrt(32) * log2(e)
#pragma unroll
    for (int m = 0; m < 4; ++m) {
#pragma unroll
        for (int n = 0; n < 4; ++n) {
            int col = nc0 + n * 16 + lm;
            int h = col >> 5, d = col & 31;
#pragma unroll
            for (int r = 0; r < 4; ++r) {
                int row = mt * 64 + m * 16 + lg * 4 + r;
                int b_ = row >> 11, tr = row & 2047;
                size_t bh = (size_t)(b_ * 8 + h) * 65536;   // 2048*32 per (b,h)
                if (which == 0) {
                    qb[bh + (size_t)tr * 32 + d] = (__bf16)(acc[m][n][r] * QS);
                } else if (which == 1) {
                    size_t idx = ((size_t)(tr >> 5) * 128 + (d >> 4) * 64 + ((d >> 3) & 1) * 32 + (tr & 31)) * 8 + (d & 7);
                    kb[bh + idx] = (__bf16)acc[m][n][r];
                } else {
                    size_t idx = ((size_t)(tr >> 5) * 256 + ((tr >> 3) & 3) * 64 + ((tr >> 2) & 1) * 32 + d) * 4 + (tr & 3);
                    vb[bh + idx] = (__bf16)acc[m][n][r];
                }
            }
        }
    }
}

// ---------------- kernel 2: attention, 32x32 swapped-operand, coalesced frags ----
// XCD swizzle: bh = (i&7)+8*(i>>9) -> each XCD serves one head, 4 batches
// (K/V + f32 bias-quad table ~1.3 MB, L2-resident).
// f32 bias quads land directly in the MFMA C-init (no unpack VALU).
__global__ __launch_bounds__(256) void k_attn(const __bf16* __restrict__ qb,
                                              const __bf16* __restrict__ kb,
                                              const __bf16* __restrict__ vb,
                                              const float4* __restrict__ btqall,
                                              __bf16* __restrict__ attn) {
    int i = blockIdx.x;
    int bh = (i & 7) + ((i >> 9) << 3);  // XCD-local head grouping (bijective)
    int qs = (i >> 3) & 63;              // q-strip 0..63
    int b_ = bh >> 3, h = bh & 7;
    int w = threadIdx.x >> 6;   // wave = k-quarter
    int lane = threadIdx.x & 63;
    int lq = lane & 31;
    int hf = lane >> 5;
    int q0 = qs * 32;

    const __bf16* qbase = qb + (size_t)bh * NTOK * 32;
    const __bf16* kbase = kb + (size_t)bh * NTOK * 32;
    const __bf16* vbase = vb + (size_t)bh * NTOK * 32;
    const float4* btq = btqall + h * HTAB;

    // Q B-frags (col=lane&31=q, k=8*hf+j), d-chunks 0 and 1 — loop invariant
    bf16x8 qf0 = *(const bf16x8*)(qbase + (size_t)(q0 + lq) * 32 + hf * 8);
    bf16x8 qf1 = *(const bf16x8*)(qbase + (size_t)(q0 + lq) * 32 + 16 + hf * 8);

    int qg = q0 + lq;
    // loop-invariant part of bias index J (includes -4hf of the k-token code)
    int qidx4 = (qg >> 8) * 961 + ((qg >> 4) & 15) * 31 + (qg & 15) + 7207 - 4 * hf;

    f32x16 Oacc, Lacc;
#pragma unroll
    for (int j = 0; j < 16; ++j) { Oacc[j] = 0.f; Lacc[j] = 0.f; }

    bf16x8 ones;
#pragma unroll
    for (int j = 0; j < 8; ++j) ones[j] = (__bf16)1.0f;

    // ---- pipeline registers: bias quads + K frags for the CURRENT iter ----
    f32x4 cb0, cb1, cb2, cb3;
    bf16x8 ck0, ck1;
    {
        int t0 = w * 512;
        int tt = t0 >> 5;
        int c00 = (t0 >> 8) * 961 + ((t0 >> 4) & 15) * 31;
        int jb = qidx4 - c00;
        cb0 = *(const f32x4*)&btq[jb - 3];
        cb1 = *(const f32x4*)&btq[jb - 11];
        cb2 = *(const f32x4*)&btq[jb - 34];
        cb3 = *(const f32x4*)&btq[jb - 42];
        const __bf16* kt = kbase + ((size_t)tt * 128 + lane) * 8;
        ck0 = *(const bf16x8*)(kt);
        ck1 = *(const bf16x8*)(kt + 512);   // j=1: +64 units * 8
    }

#pragma unroll
    for (int it = 0; it < 16; ++it) {
        int t0 = w * 512 + it * 32;
        int tt = t0 >> 5;

        // ---- prefetch iter+1 (issued before any use of current loads) ----
        f32x4 nb0, nb1, nb2, nb3;
        bf16x8 nk0, nk1;
        if (it < 15) {
            int t1 = t0 + 32;
            int c01 = (t1 >> 8) * 961 + ((t1 >> 4) & 15) * 31;
            int jb1 = qidx4 - c01;
            nb0 = *(const f32x4*)&btq[jb1 - 3];
            nb1 = *(const f32x4*)&btq[jb1 - 11];
            nb2 = *(const f32x4*)&btq[jb1 - 34];
            nb3 = *(const f32x4*)&btq[jb1 - 42];
            const __bf16* kt1 = kbase + ((size_t)(tt + 1) * 128 + lane) * 8;
            nk0 = *(const bf16x8*)(kt1);
            nk1 = *(const bf16x8*)(kt1 + 512);
        }

        // ---- V frags for THIS iter (contiguous: unit = tt*256 + g*64 + lane) ----
        const __bf16* vt = vbase + ((size_t)tt * 256 + lane) * 4;
        uint2 va  = *(const uint2*)(vt);          // g=0
        uint2 vbq = *(const uint2*)(vt + 256);    // g=1
        uint2 vc  = *(const uint2*)(vt + 512);    // g=2
        uint2 vd  = *(const uint2*)(vt + 768);    // g=3
        uint32x4 vw0 = {va.x, va.y, vbq.x, vbq.y};
        uint32x4 vw1 = {vc.x, vc.y, vd.x, vd.y};
        bf16x8 vf0 = __builtin_bit_cast(bf16x8, vw0);
        bf16x8 vf1 = __builtin_bit_cast(bf16x8, vw1);

        // ---- S = bias-init (direct f32 quads), then QK^T ----
        f32x16 S;
        S[0]  = cb0[0]; S[1]  = cb0[1]; S[2]  = cb0[2]; S[3]  = cb0[3];
        S[4]  = cb1[0]; S[5]  = cb1[1]; S[6]  = cb1[2]; S[7]  = cb1[3];
        S[8]  = cb2[0]; S[9]  = cb2[1]; S[10] = cb2[2]; S[11] = cb2[3];
        S[12] = cb3[0]; S[13] = cb3[1]; S[14] = cb3[2]; S[15] = cb3[3];
        S = mfma32(ck0, qf0, S);
        S = mfma32(ck1, qf1, S);

        // ---- P = exp2(S) -> packed bf16 pairs ----
        unsigned W0 = pkbf16(fexp2(S[0]),  fexp2(S[1]));
        unsigned W1 = pkbf16(fexp2(S[2]),  fexp2(S[3]));
        unsigned W2 = pkbf16(fexp2(S[4]),  fexp2(S[5]));
        unsigned W3 = pkbf16(fexp2(S[6]),  fexp2(S[7]));
        unsigned W4 = pkbf16(fexp2(S[8]),  fexp2(S[9]));
        unsigned W5 = pkbf16(fexp2(S[10]), fexp2(S[11]));
        unsigned W6 = pkbf16(fexp2(S[12]), fexp2(S[13]));
        unsigned W7 = pkbf16(fexp2(S[14]), fexp2(S[15]));
        uint32x4 pw0 = {W0, W1, W2, W3};
        uint32x4 pw1 = {W4, W5, W6, W7};
        bf16x8 pf0 = __builtin_bit_cast(bf16x8, pw0);
        bf16x8 pf1 = __builtin_bit_cast(bf16x8, pw1);

        Oacc = mfma32(vf0, pf0, Oacc);   // O^T[d][q] += V^T . P (common token perm)
        Oacc = mfma32(vf1, pf1, Oacc);
        Lacc = mfma32(ones, pf0, Lacc);  // every reg = lsum[q] partial
        Lacc = mfma32(ones, pf1, Lacc);

        // ---- rotate pipeline ----
        if (it < 15) {
            cb0 = nb0; cb1 = nb1; cb2 = nb2; cb3 = nb3;
            ck0 = nk0; ck1 = nk1;
        }
    }

    // ---- combine 4 k-partials via LDS ----
    __shared__ float part[4][64][17];   // 16 O + 1 lsum; stride 17 (odd -> bank-friendly)
#pragma unroll
    for (int j = 0; j < 4; ++j) {
        float4 t;
        t.x = Oacc[4 * j]; t.y = Oacc[4 * j + 1]; t.z = Oacc[4 * j + 2]; t.w = Oacc[4 * j + 3];
        *(float4*)&part[w][lane][4 * j] = t;
    }
    part[w][lane][16] = Lacc[0];
    __syncthreads();

    float4 o = {0.f, 0.f, 0.f, 0.f};
    float ls = 0.f;
#pragma unroll
    for (int sw = 0; sw < 4; ++sw) {
        float4 t = *(const float4*)&part[sw][lane][4 * w];
        o.x += t.x; o.y += t.y; o.z += t.z; o.w += t.w;
        ls += part[sw][lane][16];
    }
    float inv = 1.0f / ls;
    // wave w keeps regs 4w..4w+3 -> d = r + 8w + 4hf
    unsigned lo = pkbf16(o.x * inv, o.y * inv);
    unsigned hi = pkbf16(o.z * inv, o.w * inv);
    size_t base = ((size_t)b_ * NTOK + q0 + lq) * 256 + h * 32 + 8 * w + 4 * hf;
    *(uint2*)(attn + base) = make_uint2(lo, hi);
}

// ---------------- kernel 3: output projection -> fp32, 64x64 tile per wave ------
__global__ __launch_bounds__(256) void k_out(const __bf16* __restrict__ attn,
                                             const __bf16* __restrict__ woT,
                                             float* __restrict__ out) {
    int wid = blockIdx.x * 4 + (threadIdx.x >> 6);   // 0..511
    int lane = threadIdx.x & 63;
    int ng = wid & 3, mt = wid >> 2;                 // mt 0..127
    int lm = lane & 15, lg = lane >> 4, lk = lg * 8;
    int nc0 = ng * 64;

    f32x4 acc[4][4];
#pragma unroll
    for (int m = 0; m < 4; ++m)
#pragma unroll
        for (int n = 0; n < 4; ++n) acc[m][n] = (f32x4){0.f, 0.f, 0.f, 0.f};

    const __bf16* arow = attn + (size_t)(mt * 64 + lm) * 256 + lk;
    const __bf16* brow = woT + (size_t)(nc0 + lm) * 256 + lk;
#pragma unroll
    for (int kk = 0; kk < 8; ++kk) {
        bf16x8 a[4], b[4];
#pragma unroll
        for (int m = 0; m < 4; ++m) a[m] = *(const bf16x8*)(arow + (size_t)m * 16 * 256 + kk * 32);
#pragma unroll
        for (int n = 0; n < 4; ++n) b[n] = *(const bf16x8*)(brow + (size_t)n * 16 * 256 + kk * 32);
#pragma unroll
        for (int m = 0; m < 4; ++m)
#pragma unroll
            for (int n = 0; n < 4; ++n) acc[m][n] = mfma16(a[m], b[n], acc[m][n]);
    }
#pragma unroll
    for (int m = 0; m < 4; ++m) {
#pragma unroll
        for (int n = 0; n < 4; ++n) {
            int col = nc0 + n * 16 + lm;
#pragma unroll
            for (int r = 0; r < 4; ++r) {
                int row = mt * 64 + m * 16 + lg * 4 + r;
                out[(size_t)row * 256 + col] = acc[m][n][r];
            }
        }
    }
}

extern "C" void kernel_launch(void* const* d_in, const int* in_sizes, int n_in,
                              void* d_out, int out_size, void* d_ws, size_t ws_size,
                              hipStream_t stream) {
    const float* x    = (const float*)d_in[0];
    const float* Wq   = (const float*)d_in[1];
    const float* Wk   = (const float*)d_in[2];
    const float* Wv   = (const float*)d_in[3];
    const float* Wo   = (const float*)d_in[4];
    const float* bias = (const float*)d_in[5];
    float* out = (float*)d_out;

    __bf16* ws  = (__bf16*)d_ws;
    __bf16* xb  = ws;                       // 2,097,152 bf16 (reused as att)
    __bf16* wqT = xb  + 2097152;
    __bf16* wkT = wqT + 65536;
    __bf16* wvT = wkT + 65536;
    __bf16* woT = wvT + 65536;
    __bf16* qb  = woT + 65536;              // (b,h,n,32)
    __bf16* kb  = qb  + 2097152;            // (b,h) fragment-major K tiles
    __bf16* vb  = kb  + 2097152;            // (b,h) fragment-major V tiles
    float4* btq = (float4*)(vb + 2097152);  // 115320 x 16B f32 bias quads
    __bf16* att = xb;                       // alias: xb dead after k_qkv

    k_cvt_x<<<2048, 256, 0, stream>>>(x, xb);
    k_cvt_w<<<1024, 256, 0, stream>>>(Wq, Wk, Wv, Wo, wqT, wkT, wvT, woT);
    k_cvt_biasq<<<(NBIAS + 255) / 256, 256, 0, stream>>>(bias, btq);
    k_qkv<<<384, 256, 0, stream>>>(xb, wqT, wkT, wvT, qb, kb, vb);
    k_attn<<<2048, 256, 0, stream>>>(qb, kb, vb, btq, att);
    k_out<<<128, 256, 0, stream>>>(att, woT, out);
}

// Round 9
// 86.946 us; speedup vs baseline: 1.7182x; 1.0457x over previous
//
#include <hip/hip_runtime.h>
#include <math.h>

#define HIDDEN 256
#define NHEADS 8
#define HEAD 32
#define NTOK 2048      // tokens per batch (8*16*16)
#define NBIAS 115320   // 8 * 15 * 31 * 31
#define HTAB 14415     // 15*31*31 per-head bias entries

typedef __attribute__((ext_vector_type(8))) __bf16 bf16x8;
typedef __attribute__((ext_vector_type(4))) float f32x4;
typedef __attribute__((ext_vector_type(16))) float f32x16;
typedef __attribute__((ext_vector_type(4))) unsigned uint32x4;

static __device__ __forceinline__ f32x4 mfma16(bf16x8 a, bf16x8 b, f32x4 c) {
    return __builtin_amdgcn_mfma_f32_16x16x32_bf16(a, b, c, 0, 0, 0);
}
static __device__ __forceinline__ f32x16 mfma32(bf16x8 a, bf16x8 b, f32x16 c) {
    return __builtin_amdgcn_mfma_f32_32x32x16_bf16(a, b, c, 0, 0, 0);
}
static __device__ __forceinline__ float fexp2(float x) {
#if __has_builtin(__builtin_amdgcn_exp2f)
    return __builtin_amdgcn_exp2f(x);
#else
    return exp2f(x);
#endif
}
static __device__ __forceinline__ unsigned pkbf16(float a, float b) {
    unsigned short ua = __builtin_bit_cast(unsigned short, (__bf16)a);
    unsigned short ub = __builtin_bit_cast(unsigned short, (__bf16)b);
    return (unsigned)ua | ((unsigned)ub << 16);
}

// ---------------- kernel 0a: x fp32 -> bf16 ----------------
__global__ void k_cvt_x(const float* __restrict__ x, __bf16* __restrict__ xb) {
    int i = (blockIdx.x * blockDim.x + threadIdx.x) * 4;
    float4 v = *(const float4*)(x + i);
    xb[i + 0] = (__bf16)v.x;
    xb[i + 1] = (__bf16)v.y;
    xb[i + 2] = (__bf16)v.z;
    xb[i + 3] = (__bf16)v.w;
}

// ---------------- kernel 0b: W fp32 -> bf16, transposed (N x K) ----------------
__global__ void k_cvt_w(const float* __restrict__ w0, const float* __restrict__ w1,
                        const float* __restrict__ w2, const float* __restrict__ w3,
                        __bf16* __restrict__ t0, __bf16* __restrict__ t1,
                        __bf16* __restrict__ t2, __bf16* __restrict__ t3) {
    int wsel = blockIdx.x >> 8;
    int i = (blockIdx.x & 255) * 256 + threadIdx.x;
    const float* w = (wsel == 0) ? w0 : (wsel == 1) ? w1 : (wsel == 2) ? w2 : w3;
    __bf16* t = (wsel == 0) ? t0 : (wsel == 1) ? t1 : (wsel == 2) ? t2 : t3;
    int n = i >> 8, k = i & 255;
    t[i] = (__bf16)w[k * 256 + n];       // t[n][k] = W[k][n]
}

// ---------------- kernel 1: fused QKV projection, 64x64 tile per wave ----------
// K and V written in FRAGMENT-MAJOR tiled layouts (R7-verified):
//   K frag 16B unit at t*128 + j*64 + hf*32 + lq : K[32t+lq][8hf+16j+e]
//   V frag  8B unit at t*256 + g*64 + hf*32 + d  : V[32t+8g+4hf+s][d]
__global__ __launch_bounds__(256) void k_qkv(const __bf16* __restrict__ xb,
                                             const __bf16* __restrict__ wqT,
                                             const __bf16* __restrict__ wkT,
                                             const __bf16* __restrict__ wvT,
                                             __bf16* __restrict__ qb,
                                             __bf16* __restrict__ kb,
                                             __bf16* __restrict__ vb) {
    int wid = blockIdx.x * 4 + (threadIdx.x >> 6);   // 0..1535
    int lane = threadIdx.x & 63;
    int ng = wid % 12, mt = wid / 12;                // mt 0..127
    int lm = lane & 15, lg = lane >> 4, lk = lg * 8;
    int which = ng >> 2;
    int nc0 = (ng & 3) * 64;
    const __bf16* wT = (which == 0) ? wqT : (which == 1) ? wkT : wvT;

    f32x4 acc[4][4];
#pragma unroll
    for (int m = 0; m < 4; ++m)
#pragma unroll
        for (int n = 0; n < 4; ++n) acc[m][n] = (f32x4){0.f, 0.f, 0.f, 0.f};

    const __bf16* arow = xb + (size_t)(mt * 64 + lm) * 256 + lk;
    const __bf16* brow = wT + (size_t)(nc0 + lm) * 256 + lk;
#pragma unroll
    for (int kk = 0; kk < 8; ++kk) {
        bf16x8 a[4], b[4];
#pragma unroll
        for (int m = 0; m < 4; ++m) a[m] = *(const bf16x8*)(arow + (size_t)m * 16 * 256 + kk * 32);
#pragma unroll
        for (int n = 0; n < 4; ++n) b[n] = *(const bf16x8*)(brow + (size_t)n * 16 * 256 + kk * 32);
#pragma unroll
        for (int m = 0; m < 4; ++m)
#pragma unroll
            for (int n = 0; n < 4; ++n) acc[m][n] = mfma16(a[m], b[n], acc[m][n]);
    }
    const float QS = 0.17677669529663687f * 1.4426950408889634f;  // 1/sqrt(32) * log2(e)
#pragma unroll
    for (int m = 0; m < 4; ++m) {
#pragma unroll
        for (int n = 0; n < 4; ++n) {
            int col = nc0 + n * 16 + lm;
            int h = col >> 5, d = col & 31;
#pragma unroll
            for (int r = 0; r < 4; ++r) {
                int row = mt * 64 + m * 16 + lg * 4 + r;
                int b_ = row >> 11, tr = row & 2047;
                size_t bh = (size_t)(b_ * 8 + h) * 65536;   // 2048*32 per (b,h)
                if (which == 0) {
                    qb[bh + (size_t)tr * 32 + d] = (__bf16)(acc[m][n][r] * QS);
                } else if (which == 1) {
                    size_t idx = ((size_t)(tr >> 5) * 128 + (d >> 4) * 64 + ((d >> 3) & 1) * 32 + (tr & 31)) * 8 + (d & 7);
                    kb[bh + idx] = (__bf16)acc[m][n][r];
                } else {
                    size_t idx = ((size_t)(tr >> 5) * 256 + ((tr >> 3) & 3) * 64 + ((tr >> 2) & 1) * 32 + d) * 4 + (tr & 3);
                    vb[bh + idx] = (__bf16)acc[m][n][r];
                }
            }
        }
    }
}

// ---------------- kernel 2: attention, LDS-staged bias slice ---------------------
// Block = (b,h,q-strip of 32). The block's bias needs only Dd in [qd,qd+7],
// Dh in [qh0,qh0+16], Dw in [0,30] -> 8x17x31 f32 staged once in LDS (stride-33
// rows, w-reversed so fragment quads are 4 ascending floats). Inner loop: 16
// ds_read_b32 instead of 4 scattered 16B global gathers (the R8 L1-line hog).
// LDS region unions with the epilogue part[] buffer.
__global__ __launch_bounds__(256) void k_attn(const __bf16* __restrict__ qb,
                                              const __bf16* __restrict__ kb,
                                              const __bf16* __restrict__ vb,
                                              const float* __restrict__ bias,
                                              __bf16* __restrict__ attn) {
    int i = blockIdx.x;
    int bh = (i & 7) + ((i >> 9) << 3);  // XCD-local head grouping (bijective)
    int qs = (i >> 3) & 63;              // q-strip 0..63
    int b_ = bh >> 3, h = bh & 7;
    int w = threadIdx.x >> 6;   // wave = k-quarter
    int lane = threadIdx.x & 63;
    int lq = lane & 31;
    int hf = lane >> 5;
    int q0 = qs * 32;

    __shared__ float smem[4488];   // bias slice 8*17*33 = 4488 f32; unions part[4][64][17]=4352

    // ---- stage bias slice (x log2e), w-reversed: smem[dd*561+hh*33+(30-Dw)] ----
    {
        int qd = q0 >> 8, qh0 = (q0 >> 4) & 15;
        const float* bt = bias + h * HTAB;
        for (int t = threadIdx.x; t < 4488; t += 256) {
            int dd = t / 561, rem = t - dd * 561;
            int hh = rem / 33, ww = rem - hh * 33;
            int dw = 30 - ww; if (dw < 0) dw = 0;          // ww=31,32 pad (never read)
            smem[t] = bt[(qd + dd) * 961 + (qh0 + hh) * 31 + dw] * 1.4426950408889634f;
        }
    }
    __syncthreads();

    const __bf16* qbase = qb + (size_t)bh * NTOK * 32;
    const __bf16* kbase = kb + (size_t)bh * NTOK * 32;
    const __bf16* vbase = vb + (size_t)bh * NTOK * 32;

    // Q B-frags (col=lane&31=q, k=8*hf+j), d-chunks 0 and 1 — loop invariant
    bf16x8 qf0 = *(const bf16x8*)(qbase + (size_t)(q0 + lq) * 32 + hf * 8);
    bf16x8 qf1 = *(const bf16x8*)(qbase + (size_t)(q0 + lq) * 32 + 16 + hf * 8);

    // lane-constant part of the LDS bias address
    int lbase = (lq >> 4) * 33 + 15 - (lq & 15) + 4 * hf;

    f32x16 Oacc, Lacc;
#pragma unroll
    for (int j = 0; j < 16; ++j) { Oacc[j] = 0.f; Lacc[j] = 0.f; }

    bf16x8 ones;
#pragma unroll
    for (int j = 0; j < 8; ++j) ones[j] = (__bf16)1.0f;

    // ---- K-frag pipeline register for the CURRENT iter ----
    bf16x8 ck0, ck1;
    {
        const __bf16* kt = kbase + ((size_t)(w * 16) * 128 + lane) * 8;
        ck0 = *(const bf16x8*)(kt);
        ck1 = *(const bf16x8*)(kt + 512);
    }

#pragma unroll
    for (int it = 0; it < 16; ++it) {
        int t0 = w * 512 + it * 32;
        int tt = t0 >> 5;

        // ---- prefetch next K frags ----
        bf16x8 nk0, nk1;
        if (it < 15) {
            const __bf16* kt1 = kbase + ((size_t)(tt + 1) * 128 + lane) * 8;
            nk0 = *(const bf16x8*)(kt1);
            nk1 = *(const bf16x8*)(kt1 + 512);
        }

        // ---- V frags (contiguous: unit = tt*256 + g*64 + lane) ----
        const __bf16* vt = vbase + ((size_t)tt * 256 + lane) * 4;
        uint2 va  = *(const uint2*)(vt);
        uint2 vbq = *(const uint2*)(vt + 256);
        uint2 vc  = *(const uint2*)(vt + 512);
        uint2 vd  = *(const uint2*)(vt + 768);
        uint32x4 vw0 = {va.x, va.y, vbq.x, vbq.y};
        uint32x4 vw1 = {vc.x, vc.y, vd.x, vd.y};
        bf16x8 vf0 = __builtin_bit_cast(bf16x8, vw0);
        bf16x8 vf1 = __builtin_bit_cast(bf16x8, vw1);

        // ---- bias from LDS: reg (4g+r) <-> k-token 4hf+8g+r of this tile ----
        int kd = t0 >> 8, kh0 = (t0 >> 4) & 15;
        int a0 = (7 - kd) * 561 + (15 - kh0) * 33 + lbase;   // g0 quad base
        f32x16 S;
#pragma unroll
        for (int r = 0; r < 4; ++r) {
            S[r]      = smem[a0 + r];            // g0: kh0,  kw0=4hf
            S[4 + r]  = smem[a0 + 8 + r];        // g1: kh0,  kw0=4hf+8
            S[8 + r]  = smem[a0 - 33 + r];       // g2: kh0+1, kw0=4hf
            S[12 + r] = smem[a0 - 25 + r];       // g3: kh0+1, kw0=4hf+8
        }
        S = mfma32(ck0, qf0, S);
        S = mfma32(ck1, qf1, S);

        // ---- P = exp2(S) -> packed bf16 pairs ----
        unsigned W0 = pkbf16(fexp2(S[0]),  fexp2(S[1]));
        unsigned W1 = pkbf16(fexp2(S[2]),  fexp2(S[3]));
        unsigned W2 = pkbf16(fexp2(S[4]),  fexp2(S[5]));
        unsigned W3 = pkbf16(fexp2(S[6]),  fexp2(S[7]));
        unsigned W4 = pkbf16(fexp2(S[8]),  fexp2(S[9]));
        unsigned W5 = pkbf16(fexp2(S[10]), fexp2(S[11]));
        unsigned W6 = pkbf16(fexp2(S[12]), fexp2(S[13]));
        unsigned W7 = pkbf16(fexp2(S[14]), fexp2(S[15]));
        uint32x4 pw0 = {W0, W1, W2, W3};
        uint32x4 pw1 = {W4, W5, W6, W7};
        bf16x8 pf0 = __builtin_bit_cast(bf16x8, pw0);
        bf16x8 pf1 = __builtin_bit_cast(bf16x8, pw1);

        Oacc = mfma32(vf0, pf0, Oacc);   // O^T[d][q] += V^T . P (common token perm)
        Oacc = mfma32(vf1, pf1, Oacc);
        Lacc = mfma32(ones, pf0, Lacc);  // every reg = lsum[q] partial
        Lacc = mfma32(ones, pf1, Lacc);

        if (it < 15) { ck0 = nk0; ck1 = nk1; }
    }

    // ---- combine 4 k-partials via LDS (reuse smem as part[4][64][17]) ----
    __syncthreads();   // all waves done reading bias slice
    float (*part)[64][17] = (float (*)[64][17])smem;
#pragma unroll
    for (int j = 0; j < 4; ++j) {
        float4 t;
        t.x = Oacc[4 * j]; t.y = Oacc[4 * j + 1]; t.z = Oacc[4 * j + 2]; t.w = Oacc[4 * j + 3];
        *(float4*)&part[w][lane][4 * j] = t;
    }
    part[w][lane][16] = Lacc[0];
    __syncthreads();

    float4 o = {0.f, 0.f, 0.f, 0.f};
    float ls = 0.f;
#pragma unroll
    for (int sw = 0; sw < 4; ++sw) {
        float4 t = *(const float4*)&part[sw][lane][4 * w];
        o.x += t.x; o.y += t.y; o.z += t.z; o.w += t.w;
        ls += part[sw][lane][16];
    }
    float inv = 1.0f / ls;
    // wave w keeps regs 4w..4w+3 -> d = r + 8w + 4hf
    unsigned lo = pkbf16(o.x * inv, o.y * inv);
    unsigned hi = pkbf16(o.z * inv, o.w * inv);
    size_t base = ((size_t)b_ * NTOK + q0 + lq) * 256 + h * 32 + 8 * w + 4 * hf;
    *(uint2*)(attn + base) = make_uint2(lo, hi);
}

// ---------------- kernel 3: output projection -> fp32, 64x64 tile per wave ------
__global__ __launch_bounds__(256) void k_out(const __bf16* __restrict__ attn,
                                             const __bf16* __restrict__ woT,
                                             float* __restrict__ out) {
    int wid = blockIdx.x * 4 + (threadIdx.x >> 6);   // 0..511
    int lane = threadIdx.x & 63;
    int ng = wid & 3, mt = wid >> 2;                 // mt 0..127
    int lm = lane & 15, lg = lane >> 4, lk = lg * 8;
    int nc0 = ng * 64;

    f32x4 acc[4][4];
#pragma unroll
    for (int m = 0; m < 4; ++m)
#pragma unroll
        for (int n = 0; n < 4; ++n) acc[m][n] = (f32x4){0.f, 0.f, 0.f, 0.f};

    const __bf16* arow = attn + (size_t)(mt * 64 + lm) * 256 + lk;
    const __bf16* brow = woT + (size_t)(nc0 + lm) * 256 + lk;
#pragma unroll
    for (int kk = 0; kk < 8; ++kk) {
        bf16x8 a[4], b[4];
#pragma unroll
        for (int m = 0; m < 4; ++m) a[m] = *(const bf16x8*)(arow + (size_t)m * 16 * 256 + kk * 32);
#pragma unroll
        for (int n = 0; n < 4; ++n) b[n] = *(const bf16x8*)(brow + (size_t)n * 16 * 256 + kk * 32);
#pragma unroll
        for (int m = 0; m < 4; ++m)
#pragma unroll
            for (int n = 0; n < 4; ++n) acc[m][n] = mfma16(a[m], b[n], acc[m][n]);
    }
#pragma unroll
    for (int m = 0; m < 4; ++m) {
#pragma unroll
        for (int n = 0; n < 4; ++n) {
            int col = nc0 + n * 16 + lm;
#pragma unroll
            for (int r = 0; r < 4; ++r) {
                int row = mt * 64 + m * 16 + lg * 4 + r;
                out[(size_t)row * 256 + col] = acc[m][n][r];
            }
        }
    }
}

extern "C" void kernel_launch(void* const* d_in, const int* in_sizes, int n_in,
                              void* d_out, int out_size, void* d_ws, size_t ws_size,
                              hipStream_t stream) {
    const float* x    = (const float*)d_in[0];
    const float* Wq   = (const float*)d_in[1];
    const float* Wk   = (const float*)d_in[2];
    const float* Wv   = (const float*)d_in[3];
    const float* Wo   = (const float*)d_in[4];
    const float* bias = (const float*)d_in[5];
    float* out = (float*)d_out;

    __bf16* ws  = (__bf16*)d_ws;
    __bf16* xb  = ws;                       // 2,097,152 bf16 (reused as att)
    __bf16* wqT = xb  + 2097152;
    __bf16* wkT = wqT + 65536;
    __bf16* wvT = wkT + 65536;
    __bf16* woT = wvT + 65536;
    __bf16* qb  = woT + 65536;              // (b,h,n,32)
    __bf16* kb  = qb  + 2097152;            // (b,h) fragment-major K tiles
    __bf16* vb  = kb  + 2097152;            // (b,h) fragment-major V tiles
    __bf16* att = xb;                       // alias: xb dead after k_qkv

    k_cvt_x<<<2048, 256, 0, stream>>>(x, xb);
    k_cvt_w<<<1024, 256, 0, stream>>>(Wq, Wk, Wv, Wo, wqT, wkT, wvT, woT);
    k_qkv<<<384, 256, 0, stream>>>(xb, wqT, wkT, wvT, qb, kb, vb);
    k_attn<<<2048, 256, 0, stream>>>(qb, kb, vb, bias, att);
    k_out<<<128, 256, 0, stream>>>(att, woT, out);
}

// Round 10
// 84.168 us; speedup vs baseline: 1.7749x; 1.0330x over previous
//
#include <hip/hip_runtime.h>
#include <math.h>

#define HIDDEN 256
#define NHEADS 8
#define HEAD 32
#define NTOK 2048      // tokens per batch (8*16*16)
#define NBIAS 115320   // 8 * 15 * 31 * 31
#define HTAB 14415     // 15*31*31 per-head bias entries

typedef __attribute__((ext_vector_type(8))) __bf16 bf16x8;
typedef __attribute__((ext_vector_type(4))) float f32x4;
typedef __attribute__((ext_vector_type(16))) float f32x16;
typedef __attribute__((ext_vector_type(4))) unsigned uint32x4;

static __device__ __forceinline__ f32x4 mfma16(bf16x8 a, bf16x8 b, f32x4 c) {
    return __builtin_amdgcn_mfma_f32_16x16x32_bf16(a, b, c, 0, 0, 0);
}
static __device__ __forceinline__ f32x16 mfma32(bf16x8 a, bf16x8 b, f32x16 c) {
    return __builtin_amdgcn_mfma_f32_32x32x16_bf16(a, b, c, 0, 0, 0);
}
static __device__ __forceinline__ float fexp2(float x) {
#if __has_builtin(__builtin_amdgcn_exp2f)
    return __builtin_amdgcn_exp2f(x);
#else
    return exp2f(x);
#endif
}
static __device__ __forceinline__ unsigned pkbf16(float a, float b) {
    unsigned short ua = __builtin_bit_cast(unsigned short, (__bf16)a);
    unsigned short ub = __builtin_bit_cast(unsigned short, (__bf16)b);
    return (unsigned)ua | ((unsigned)ub << 16);
}

// ---------------- kernel 0a: x fp32 -> bf16 ----------------
__global__ void k_cvt_x(const float* __restrict__ x, __bf16* __restrict__ xb) {
    int i = (blockIdx.x * blockDim.x + threadIdx.x) * 4;
    float4 v = *(const float4*)(x + i);
    xb[i + 0] = (__bf16)v.x;
    xb[i + 1] = (__bf16)v.y;
    xb[i + 2] = (__bf16)v.z;
    xb[i + 3] = (__bf16)v.w;
}

// ---------------- kernel 0b: W fp32 -> bf16, transposed (N x K) ----------------
__global__ void k_cvt_w(const float* __restrict__ w0, const float* __restrict__ w1,
                        const float* __restrict__ w2, const float* __restrict__ w3,
                        __bf16* __restrict__ t0, __bf16* __restrict__ t1,
                        __bf16* __restrict__ t2, __bf16* __restrict__ t3) {
    int wsel = blockIdx.x >> 8;
    int i = (blockIdx.x & 255) * 256 + threadIdx.x;
    const float* w = (wsel == 0) ? w0 : (wsel == 1) ? w1 : (wsel == 2) ? w2 : w3;
    __bf16* t = (wsel == 0) ? t0 : (wsel == 1) ? t1 : (wsel == 2) ? t2 : t3;
    int n = i >> 8, k = i & 255;
    t[i] = (__bf16)w[k * 256 + n];       // t[n][k] = W[k][n]
}

// ---------------- kernel 1: fused QKV projection, 64x64 tile per wave ----------
// K and V written in FRAGMENT-MAJOR tiled layouts (R7-verified):
//   K frag 16B unit at t*128 + j*64 + hf*32 + lq : K[32t+lq][8hf+16j+e]
//   V frag  8B unit at t*256 + g*64 + hf*32 + d  : V[32t+8g+4hf+s][d]
__global__ __launch_bounds__(256) void k_qkv(const __bf16* __restrict__ xb,
                                             const __bf16* __restrict__ wqT,
                                             const __bf16* __restrict__ wkT,
                                             const __bf16* __restrict__ wvT,
                                             __bf16* __restrict__ qb,
                                             __bf16* __restrict__ kb,
                                             __bf16* __restrict__ vb) {
    int wid = blockIdx.x * 4 + (threadIdx.x >> 6);   // 0..1535
    int lane = threadIdx.x & 63;
    int ng = wid % 12, mt = wid / 12;                // mt 0..127
    int lm = lane & 15, lg = lane >> 4, lk = lg * 8;
    int which = ng >> 2;
    int nc0 = (ng & 3) * 64;
    const __bf16* wT = (which == 0) ? wqT : (which == 1) ? wkT : wvT;

    f32x4 acc[4][4];
#pragma unroll
    for (int m = 0; m < 4; ++m)
#pragma unroll
        for (int n = 0; n < 4; ++n) acc[m][n] = (f32x4){0.f, 0.f, 0.f, 0.f};

    const __bf16* arow = xb + (size_t)(mt * 64 + lm) * 256 + lk;
    const __bf16* brow = wT + (size_t)(nc0 + lm) * 256 + lk;
#pragma unroll
    for (int kk = 0; kk < 8; ++kk) {
        bf16x8 a[4], b[4];
#pragma unroll
        for (int m = 0; m < 4; ++m) a[m] = *(const bf16x8*)(arow + (size_t)m * 16 * 256 + kk * 32);
#pragma unroll
        for (int n = 0; n < 4; ++n) b[n] = *(const bf16x8*)(brow + (size_t)n * 16 * 256 + kk * 32);
#pragma unroll
        for (int m = 0; m < 4; ++m)
#pragma unroll
            for (int n = 0; n < 4; ++n) acc[m][n] = mfma16(a[m], b[n], acc[m][n]);
    }
    const float QS = 0.17677669529663687f * 1.4426950408889634f;  // 1/sqrt(32) * log2(e)
#pragma unroll
    for (int m = 0; m < 4; ++m) {
#pragma unroll
        for (int n = 0; n < 4; ++n) {
            int col = nc0 + n * 16 + lm;
            int h = col >> 5, d = col & 31;
#pragma unroll
            for (int r = 0; r < 4; ++r) {
                int row = mt * 64 + m * 16 + lg * 4 + r;
                int b_ = row >> 11, tr = row & 2047;
                size_t bh = (size_t)(b_ * 8 + h) * 65536;   // 2048*32 per (b,h)
                if (which == 0) {
                    qb[bh + (size_t)tr * 32 + d] = (__bf16)(acc[m][n][r] * QS);
                } else if (which == 1) {
                    size_t idx = ((size_t)(tr >> 5) * 128 + (d >> 4) * 64 + ((d >> 3) & 1) * 32 + (tr & 31)) * 8 + (d & 7);
                    kb[bh + idx] = (__bf16)acc[m][n][r];
                } else {
                    size_t idx = ((size_t)(tr >> 5) * 256 + ((tr >> 3) & 3) * 64 + ((tr >> 2) & 1) * 32 + d) * 4 + (tr & 3);
                    vb[bh + idx] = (__bf16)acc[m][n][r];
                }
            }
        }
    }
}

// ---------------- kernel 2: attention, 64q/block, K/V reused across 2 strips ----
// Block = (b,h, 64 queries). Each wave = one k-quarter x BOTH q-strips: K and V
// fragments are loaded once and feed 2x QK^T + 2x PV (12 MFMA per 4 KB loaded,
// 2x the math/byte of R9). Bias slice 8x19x33 f32 in LDS; strip B reads +66.
__global__ __launch_bounds__(256) void k_attn(const __bf16* __restrict__ qb,
                                              const __bf16* __restrict__ kb,
                                              const __bf16* __restrict__ vb,
                                              const float* __restrict__ bias,
                                              __bf16* __restrict__ attn) {
    int i = blockIdx.x;
    int x = i & 7, r_ = i >> 3;          // 1024 blocks: XCD x serves bh {x,x+8,x+16,x+24}
    int bh = x + ((r_ >> 5) << 3);
    int qblk = r_ & 31;                  // 64-query block
    int b_ = bh >> 3, h = bh & 7;
    int w = threadIdx.x >> 6;            // wave = k-quarter
    int lane = threadIdx.x & 63;
    int lq = lane & 31;
    int hf = lane >> 5;
    int q0 = qblk * 64;

    __shared__ float smem[5016];   // bias slice 8*19*33; unions part[4][64][17]=4352

    // ---- stage bias slice (x log2e), w-reversed: smem[dd*627+hh*33+ww] ----
    {
        int qd = q0 >> 8, qh0 = (q0 >> 4) & 15;   // qh0 in {0,4,8,12}
        const float* bt = bias + h * HTAB;
        for (int t = threadIdx.x; t < 5016; t += 256) {
            int dd = t / 627, rem = t - dd * 627;
            int hh = rem / 33, ww = rem - hh * 33;
            int dw = 30 - ww; if (dw < 0) dw = 0;          // ww=31,32 pad (never read)
            smem[t] = bt[(qd + dd) * 961 + (qh0 + hh) * 31 + dw] * 1.4426950408889634f;
        }
    }
    __syncthreads();

    const __bf16* qbase = qb + (size_t)bh * NTOK * 32;
    const __bf16* kbase = kb + (size_t)bh * NTOK * 32;
    const __bf16* vbase = vb + (size_t)bh * NTOK * 32;

    // Q B-frags for both strips (col=lane&31=q, k=8*hf+j), d-chunks 0,1
    bf16x8 qfA0 = *(const bf16x8*)(qbase + (size_t)(q0 + lq) * 32 + hf * 8);
    bf16x8 qfA1 = *(const bf16x8*)(qbase + (size_t)(q0 + lq) * 32 + 16 + hf * 8);
    bf16x8 qfB0 = *(const bf16x8*)(qbase + (size_t)(q0 + 32 + lq) * 32 + hf * 8);
    bf16x8 qfB1 = *(const bf16x8*)(qbase + (size_t)(q0 + 32 + lq) * 32 + 16 + hf * 8);

    // lane-constant part of the LDS bias address
    int lbase = (lq >> 4) * 33 + 15 - (lq & 15) + 4 * hf;

    f32x16 OaccA, LaccA, OaccB, LaccB;
#pragma unroll
    for (int j = 0; j < 16; ++j) { OaccA[j] = 0.f; LaccA[j] = 0.f; OaccB[j] = 0.f; LaccB[j] = 0.f; }

    bf16x8 ones;
#pragma unroll
    for (int j = 0; j < 8; ++j) ones[j] = (__bf16)1.0f;

    // ---- K-frag pipeline register for the CURRENT iter ----
    bf16x8 ck0, ck1;
    {
        const __bf16* kt = kbase + ((size_t)(w * 16) * 128 + lane) * 8;
        ck0 = *(const bf16x8*)(kt);
        ck1 = *(const bf16x8*)(kt + 512);
    }

#pragma unroll
    for (int it = 0; it < 16; ++it) {
        int t0 = w * 512 + it * 32;
        int tt = t0 >> 5;

        // ---- prefetch next K frags ----
        bf16x8 nk0, nk1;
        if (it < 15) {
            const __bf16* kt1 = kbase + ((size_t)(tt + 1) * 128 + lane) * 8;
            nk0 = *(const bf16x8*)(kt1);
            nk1 = *(const bf16x8*)(kt1 + 512);
        }

        // ---- V frags (contiguous: unit = tt*256 + g*64 + lane), shared by strips --
        const __bf16* vt = vbase + ((size_t)tt * 256 + lane) * 4;
        uint2 va  = *(const uint2*)(vt);
        uint2 vbq = *(const uint2*)(vt + 256);
        uint2 vc  = *(const uint2*)(vt + 512);
        uint2 vd  = *(const uint2*)(vt + 768);
        uint32x4 vw0 = {va.x, va.y, vbq.x, vbq.y};
        uint32x4 vw1 = {vc.x, vc.y, vd.x, vd.y};
        bf16x8 vf0 = __builtin_bit_cast(bf16x8, vw0);
        bf16x8 vf1 = __builtin_bit_cast(bf16x8, vw1);

        // ---- bias from LDS: reg (4g+r) <-> k-token 4hf+8g+r; strip B at +66 ----
        int kd = t0 >> 8, kh0 = (t0 >> 4) & 15;
        int a0 = (7 - kd) * 627 + (15 - kh0) * 33 + lbase;
        f32x16 SA, SB;
#pragma unroll
        for (int r = 0; r < 4; ++r) {
            SA[r]      = smem[a0 + r];
            SA[4 + r]  = smem[a0 + 8 + r];
            SA[8 + r]  = smem[a0 - 33 + r];
            SA[12 + r] = smem[a0 - 25 + r];
            SB[r]      = smem[a0 + 66 + r];
            SB[4 + r]  = smem[a0 + 74 + r];
            SB[8 + r]  = smem[a0 + 33 + r];
            SB[12 + r] = smem[a0 + 41 + r];
        }
        SA = mfma32(ck0, qfA0, SA);
        SA = mfma32(ck1, qfA1, SA);
        SB = mfma32(ck0, qfB0, SB);
        SB = mfma32(ck1, qfB1, SB);

        // ---- strip A: P = exp2(S) -> bf16 -> PV ----
        {
            unsigned W0 = pkbf16(fexp2(SA[0]),  fexp2(SA[1]));
            unsigned W1 = pkbf16(fexp2(SA[2]),  fexp2(SA[3]));
            unsigned W2 = pkbf16(fexp2(SA[4]),  fexp2(SA[5]));
            unsigned W3 = pkbf16(fexp2(SA[6]),  fexp2(SA[7]));
            unsigned W4 = pkbf16(fexp2(SA[8]),  fexp2(SA[9]));
            unsigned W5 = pkbf16(fexp2(SA[10]), fexp2(SA[11]));
            unsigned W6 = pkbf16(fexp2(SA[12]), fexp2(SA[13]));
            unsigned W7 = pkbf16(fexp2(SA[14]), fexp2(SA[15]));
            uint32x4 pw0 = {W0, W1, W2, W3};
            uint32x4 pw1 = {W4, W5, W6, W7};
            bf16x8 pf0 = __builtin_bit_cast(bf16x8, pw0);
            bf16x8 pf1 = __builtin_bit_cast(bf16x8, pw1);
            OaccA = mfma32(vf0, pf0, OaccA);
            OaccA = mfma32(vf1, pf1, OaccA);
            LaccA = mfma32(ones, pf0, LaccA);
            LaccA = mfma32(ones, pf1, LaccA);
        }
        // ---- strip B ----
        {
            unsigned W0 = pkbf16(fexp2(SB[0]),  fexp2(SB[1]));
            unsigned W1 = pkbf16(fexp2(SB[2]),  fexp2(SB[3]));
            unsigned W2 = pkbf16(fexp2(SB[4]),  fexp2(SB[5]));
            unsigned W3 = pkbf16(fexp2(SB[6]),  fexp2(SB[7]));
            unsigned W4 = pkbf16(fexp2(SB[8]),  fexp2(SB[9]));
            unsigned W5 = pkbf16(fexp2(SB[10]), fexp2(SB[11]));
            unsigned W6 = pkbf16(fexp2(SB[12]), fexp2(SB[13]));
            unsigned W7 = pkbf16(fexp2(SB[14]), fexp2(SB[15]));
            uint32x4 pw0 = {W0, W1, W2, W3};
            uint32x4 pw1 = {W4, W5, W6, W7};
            bf16x8 pf0 = __builtin_bit_cast(bf16x8, pw0);
            bf16x8 pf1 = __builtin_bit_cast(bf16x8, pw1);
            OaccB = mfma32(vf0, pf0, OaccB);
            OaccB = mfma32(vf1, pf1, OaccB);
            LaccB = mfma32(ones, pf0, LaccB);
            LaccB = mfma32(ones, pf1, LaccB);
        }

        if (it < 15) { ck0 = nk0; ck1 = nk1; }
    }

    // ---- combine 4 k-partials via LDS (reuse smem as part[4][64][17]) ----
    float (*part)[64][17] = (float (*)[64][17])smem;
#pragma unroll
    for (int s = 0; s < 2; ++s) {
        f32x16* O = s ? &OaccB : &OaccA;
        f32x16* L = s ? &LaccB : &LaccA;
        __syncthreads();   // previous phase (bias reads / prior strip) done
#pragma unroll
        for (int j = 0; j < 4; ++j) {
            float4 t;
            t.x = (*O)[4 * j]; t.y = (*O)[4 * j + 1]; t.z = (*O)[4 * j + 2]; t.w = (*O)[4 * j + 3];
            *(float4*)&part[w][lane][4 * j] = t;
        }
        part[w][lane][16] = (*L)[0];
        __syncthreads();

        float4 o = {0.f, 0.f, 0.f, 0.f};
        float ls = 0.f;
#pragma unroll
        for (int sw = 0; sw < 4; ++sw) {
            float4 t = *(const float4*)&part[sw][lane][4 * w];
            o.x += t.x; o.y += t.y; o.z += t.z; o.w += t.w;
            ls += part[sw][lane][16];
        }
        float inv = 1.0f / ls;
        unsigned lo = pkbf16(o.x * inv, o.y * inv);
        unsigned hi = pkbf16(o.z * inv, o.w * inv);
        size_t base = ((size_t)b_ * NTOK + q0 + 32 * s + lq) * 256 + h * 32 + 8 * w + 4 * hf;
        *(uint2*)(attn + base) = make_uint2(lo, hi);
    }
}

// ---------------- kernel 3: output projection -> fp32, 64x64 tile per wave ------
__global__ __launch_bounds__(256) void k_out(const __bf16* __restrict__ attn,
                                             const __bf16* __restrict__ woT,
                                             float* __restrict__ out) {
    int wid = blockIdx.x * 4 + (threadIdx.x >> 6);   // 0..511
    int lane = threadIdx.x & 63;
    int ng = wid & 3, mt = wid >> 2;                 // mt 0..127
    int lm = lane & 15, lg = lane >> 4, lk = lg * 8;
    int nc0 = ng * 64;

    f32x4 acc[4][4];
#pragma unroll
    for (int m = 0; m < 4; ++m)
#pragma unroll
        for (int n = 0; n < 4; ++n) acc[m][n] = (f32x4){0.f, 0.f, 0.f, 0.f};

    const __bf16* arow = attn + (size_t)(mt * 64 + lm) * 256 + lk;
    const __bf16* brow = woT + (size_t)(nc0 + lm) * 256 + lk;
#pragma unroll
    for (int kk = 0; kk < 8; ++kk) {
        bf16x8 a[4], b[4];
#pragma unroll
        for (int m = 0; m < 4; ++m) a[m] = *(const bf16x8*)(arow + (size_t)m * 16 * 256 + kk * 32);
#pragma unroll
        for (int n = 0; n < 4; ++n) b[n] = *(const bf16x8*)(brow + (size_t)n * 16 * 256 + kk * 32);
#pragma unroll
        for (int m = 0; m < 4; ++m)
#pragma unroll
            for (int n = 0; n < 4; ++n) acc[m][n] = mfma16(a[m], b[n], acc[m][n]);
    }
#pragma unroll
    for (int m = 0; m < 4; ++m) {
#pragma unroll
        for (int n = 0; n < 4; ++n) {
            int col = nc0 + n * 16 + lm;
#pragma unroll
            for (int r = 0; r < 4; ++r) {
                int row = mt * 64 + m * 16 + lg * 4 + r;
                out[(size_t)row * 256 + col] = acc[m][n][r];
            }
        }
    }
}

extern "C" void kernel_launch(void* const* d_in, const int* in_sizes, int n_in,
                              void* d_out, int out_size, void* d_ws, size_t ws_size,
                              hipStream_t stream) {
    const float* x    = (const float*)d_in[0];
    const float* Wq   = (const float*)d_in[1];
    const float* Wk   = (const float*)d_in[2];
    const float* Wv   = (const float*)d_in[3];
    const float* Wo   = (const float*)d_in[4];
    const float* bias = (const float*)d_in[5];
    float* out = (float*)d_out;

    __bf16* ws  = (__bf16*)d_ws;
    __bf16* xb  = ws;                       // 2,097,152 bf16 (reused as att)
    __bf16* wqT = xb  + 2097152;
    __bf16* wkT = wqT + 65536;
    __bf16* wvT = wkT + 65536;
    __bf16* woT = wvT + 65536;
    __bf16* qb  = woT + 65536;              // (b,h,n,32)
    __bf16* kb  = qb  + 2097152;            // (b,h) fragment-major K tiles
    __bf16* vb  = kb  + 2097152;            // (b,h) fragment-major V tiles
    __bf16* att = xb;                       // alias: xb dead after k_qkv

    k_cvt_x<<<2048, 256, 0, stream>>>(x, xb);
    k_cvt_w<<<1024, 256, 0, stream>>>(Wq, Wk, Wv, Wo, wqT, wkT, wvT, woT);
    k_qkv<<<384, 256, 0, stream>>>(xb, wqT, wkT, wvT, qb, kb, vb);
    k_attn<<<1024, 256, 0, stream>>>(qb, kb, vb, bias, att);
    k_out<<<128, 256, 0, stream>>>(att, woT, out);
}

// Round 11
// 78.168 us; speedup vs baseline: 1.9112x; 1.0768x over previous
//
#include <hip/hip_runtime.h>
#include <math.h>

#define HIDDEN 256
#define NHEADS 8
#define HEAD 32
#define NTOK 2048      // tokens per batch (8*16*16)
#define NBIAS 115320   // 8 * 15 * 31 * 31
#define HTAB 14415     // 15*31*31 per-head bias entries

typedef __attribute__((ext_vector_type(8))) __bf16 bf16x8;
typedef __attribute__((ext_vector_type(4))) float f32x4;
typedef __attribute__((ext_vector_type(16))) float f32x16;
typedef __attribute__((ext_vector_type(4))) unsigned uint32x4;

static __device__ __forceinline__ f32x4 mfma16(bf16x8 a, bf16x8 b, f32x4 c) {
    return __builtin_amdgcn_mfma_f32_16x16x32_bf16(a, b, c, 0, 0, 0);
}
static __device__ __forceinline__ f32x16 mfma32(bf16x8 a, bf16x8 b, f32x16 c) {
    return __builtin_amdgcn_mfma_f32_32x32x16_bf16(a, b, c, 0, 0, 0);
}
static __device__ __forceinline__ float fexp2(float x) {
#if __has_builtin(__builtin_amdgcn_exp2f)
    return __builtin_amdgcn_exp2f(x);
#else
    return exp2f(x);
#endif
}
static __device__ __forceinline__ unsigned pkbf16(float a, float b) {
    unsigned short ua = __builtin_bit_cast(unsigned short, (__bf16)a);
    unsigned short ub = __builtin_bit_cast(unsigned short, (__bf16)b);
    return (unsigned)ua | ((unsigned)ub << 16);
}

// ---------------- kernel 0: fused input/weight conversion ----------------
// blocks [0,2048): x fp32 -> bf16 (float4 per thread)
// blocks [2048,3072): W fp32 -> bf16 transposed (N x K)
__global__ void k_prep(const float* __restrict__ x, const float* __restrict__ w0,
                       const float* __restrict__ w1, const float* __restrict__ w2,
                       const float* __restrict__ w3, __bf16* __restrict__ xb,
                       __bf16* __restrict__ t0, __bf16* __restrict__ t1,
                       __bf16* __restrict__ t2, __bf16* __restrict__ t3) {
    int bid = blockIdx.x;
    if (bid < 2048) {
        int i = (bid * 256 + threadIdx.x) * 4;
        float4 v = *(const float4*)(x + i);
        xb[i + 0] = (__bf16)v.x;
        xb[i + 1] = (__bf16)v.y;
        xb[i + 2] = (__bf16)v.z;
        xb[i + 3] = (__bf16)v.w;
    } else {
        int q = bid - 2048;
        int wsel = q >> 8;
        int i = (q & 255) * 256 + threadIdx.x;
        const float* w = (wsel == 0) ? w0 : (wsel == 1) ? w1 : (wsel == 2) ? w2 : w3;
        __bf16* t = (wsel == 0) ? t0 : (wsel == 1) ? t1 : (wsel == 2) ? t2 : t3;
        int n = i >> 8, k = i & 255;
        t[i] = (__bf16)w[k * 256 + n];       // t[n][k] = W[k][n]
    }
}

// ---------------- kernel 1: fused QKV projection, 64x64 tile per 1-wave block --
// K and V in FRAGMENT-MAJOR tiled layouts (R7-verified consumer contract):
//   K frag 16B unit at t*128 + j*64 + hf*32 + lq : K[32t+lq][8hf+16j+e]
//   V frag  8B unit at t*256 + g*64 + hf*32 + d  : V[32t+8g+4hf+s][d]
// NEW: acc -> wave-private LDS tile -> coalesced 16B-per-lane contiguous stores
// (replaces 64 scattered scalar stores per wave).
__global__ __launch_bounds__(64) void k_qkv(const __bf16* __restrict__ xb,
                                            const __bf16* __restrict__ wqT,
                                            const __bf16* __restrict__ wkT,
                                            const __bf16* __restrict__ wvT,
                                            __bf16* __restrict__ qb,
                                            __bf16* __restrict__ kb,
                                            __bf16* __restrict__ vb) {
    int wid = blockIdx.x;                // 0..1535
    int lane = threadIdx.x;              // 0..63
    int ng = wid % 12, mt = wid / 12;    // mt 0..127
    int lm = lane & 15, lg = lane >> 4, lk = lg * 8;
    int which = ng >> 2;
    int nc0 = (ng & 3) * 64;
    const __bf16* wT = (which == 0) ? wqT : (which == 1) ? wkT : wvT;

    f32x4 acc[4][4];
#pragma unroll
    for (int m = 0; m < 4; ++m)
#pragma unroll
        for (int n = 0; n < 4; ++n) acc[m][n] = (f32x4){0.f, 0.f, 0.f, 0.f};

    const __bf16* arow = xb + (size_t)(mt * 64 + lm) * 256 + lk;
    const __bf16* brow = wT + (size_t)(nc0 + lm) * 256 + lk;
#pragma unroll
    for (int kk = 0; kk < 8; ++kk) {
        bf16x8 a[4], b[4];
#pragma unroll
        for (int m = 0; m < 4; ++m) a[m] = *(const bf16x8*)(arow + (size_t)m * 16 * 256 + kk * 32);
#pragma unroll
        for (int n = 0; n < 4; ++n) b[n] = *(const bf16x8*)(brow + (size_t)n * 16 * 256 + kk * 32);
#pragma unroll
        for (int m = 0; m < 4; ++m)
#pragma unroll
            for (int n = 0; n < 4; ++n) acc[m][n] = mfma16(a[m], b[n], acc[m][n]);
    }

    int b_ = mt >> 5;              // batch
    int tb = (mt & 31) * 2;        // first 32-token tile within batch
    int h0 = nc0 >> 5;             // first head of the 64-col strip

    __shared__ __attribute__((aligned(16))) __bf16 tile[4608];   // 64 x 72

    if (which == 0) {
        const float QS = 0.17677669529663687f * 1.4426950408889634f;  // 1/sqrt(32)*log2e
#pragma unroll
        for (int m = 0; m < 4; ++m)
#pragma unroll
            for (int n = 0; n < 4; ++n) {
                int col = nc0 + n * 16 + lm;
                int h = col >> 5, d = col & 31;
#pragma unroll
                for (int r = 0; r < 4; ++r) {
                    int row = mt * 64 + m * 16 + lg * 4 + r;
                    qb[(size_t)(b_ * 8 + h) * 65536 + (size_t)(row & 2047) * 32 + d] =
                        (__bf16)(acc[m][n][r] * QS);
                }
            }
        return;
    }

    // ---- stage tile in LDS: K row-major [row][col], V col-major [col][row] ----
#pragma unroll
    for (int m = 0; m < 4; ++m)
#pragma unroll
        for (int n = 0; n < 4; ++n)
#pragma unroll
            for (int r = 0; r < 4; ++r) {
                int row = m * 16 + lg * 4 + r;
                int col = n * 16 + lm;
                if (which == 1) tile[row * 72 + col] = (__bf16)acc[m][n][r];
                else            tile[col * 72 + row] = (__bf16)acc[m][n][r];
            }
    __syncthreads();   // single wave: cheap; orders LDS writes vs reads

    if (which == 1) {
        // K: per (t_local, head_local) 128 16B-units contiguous (2 KB)
#pragma unroll
        for (int tl = 0; tl < 2; ++tl)
#pragma unroll
            for (int hl = 0; hl < 2; ++hl) {
                size_t gb = (size_t)(b_ * 8 + h0 + hl) * 65536 + (size_t)(tb + tl) * 1024;
#pragma unroll
                for (int half = 0; half < 2; ++half) {
                    int u = half * 64 + lane;              // 0..127
                    int j = u >> 6, hf2 = (u >> 5) & 1, lq2 = u & 31;
                    bf16x8 vv = *(const bf16x8*)&tile[(tl * 32 + lq2) * 72 + hl * 32 + 16 * j + 8 * hf2];
                    *(bf16x8*)(kb + gb + (size_t)u * 8) = vv;
                }
            }
    } else {
        // V: per (t_local, head_local) 256 8B-units contiguous; store b128 pairs
#pragma unroll
        for (int tl = 0; tl < 2; ++tl)
#pragma unroll
            for (int hl = 0; hl < 2; ++hl) {
                size_t gb = (size_t)(b_ * 8 + h0 + hl) * 65536 + (size_t)(tb + tl) * 1024;
#pragma unroll
                for (int half = 0; half < 2; ++half) {
                    int u0 = (half * 64 + lane) * 2;       // even unit 0..254
                    int g = u0 >> 6, hf2 = (u0 >> 5) & 1, d0 = u0 & 31;
                    const __bf16* pl = &tile[(hl * 32 + d0) * 72 + tl * 32 + 8 * g + 4 * hf2];
                    uint2 lo = *(const uint2*)pl;          // d0
                    uint2 hi = *(const uint2*)(pl + 72);   // d0+1
                    uint32x4 sv = {lo.x, lo.y, hi.x, hi.y};
                    *(uint32x4*)(vb + gb + (size_t)u0 * 4) = sv;
                }
            }
    }
}

// ---------------- kernel 2: attention, 64q/block, pipelined bias C-init --------
// Block = (b,h, 64 queries); wave = k-quarter x both strips. Bias slice 8x19x33
// f32 in LDS; the 32 C-init floats for iter+1 are prefetched right after this
// iter's QK^T so the LDS latency hides under exp/pack/PV.
__global__ __launch_bounds__(256) void k_attn(const __bf16* __restrict__ qb,
                                              const __bf16* __restrict__ kb,
                                              const __bf16* __restrict__ vb,
                                              const float* __restrict__ bias,
                                              __bf16* __restrict__ attn) {
    int i = blockIdx.x;
    int x = i & 7, r_ = i >> 3;          // XCD x serves bh {x,x+8,x+16,x+24}
    int bh = x + ((r_ >> 5) << 3);
    int qblk = r_ & 31;
    int b_ = bh >> 3, h = bh & 7;
    int w = threadIdx.x >> 6;
    int lane = threadIdx.x & 63;
    int lq = lane & 31;
    int hf = lane >> 5;
    int q0 = qblk * 64;

    __shared__ float smem[5016];   // bias slice 8*19*33; unions part[4][64][17]=4352

    {
        int qd = q0 >> 8, qh0 = (q0 >> 4) & 15;
        const float* bt = bias + h * HTAB;
        for (int t = threadIdx.x; t < 5016; t += 256) {
            int dd = t / 627, rem = t - dd * 627;
            int hh = rem / 33, ww = rem - hh * 33;
            int dw = 30 - ww; if (dw < 0) dw = 0;
            smem[t] = bt[(qd + dd) * 961 + (qh0 + hh) * 31 + dw] * 1.4426950408889634f;
        }
    }
    __syncthreads();

    const __bf16* qbase = qb + (size_t)bh * NTOK * 32;
    const __bf16* kbase = kb + (size_t)bh * NTOK * 32;
    const __bf16* vbase = vb + (size_t)bh * NTOK * 32;

    bf16x8 qfA0 = *(const bf16x8*)(qbase + (size_t)(q0 + lq) * 32 + hf * 8);
    bf16x8 qfA1 = *(const bf16x8*)(qbase + (size_t)(q0 + lq) * 32 + 16 + hf * 8);
    bf16x8 qfB0 = *(const bf16x8*)(qbase + (size_t)(q0 + 32 + lq) * 32 + hf * 8);
    bf16x8 qfB1 = *(const bf16x8*)(qbase + (size_t)(q0 + 32 + lq) * 32 + 16 + hf * 8);

    int lbase = (lq >> 4) * 33 + 15 - (lq & 15) + 4 * hf;

    f32x16 OaccA, LaccA, OaccB, LaccB;
#pragma unroll
    for (int j = 0; j < 16; ++j) { OaccA[j] = 0.f; LaccA[j] = 0.f; OaccB[j] = 0.f; LaccB[j] = 0.f; }

    bf16x8 ones;
#pragma unroll
    for (int j = 0; j < 8; ++j) ones[j] = (__bf16)1.0f;

    // bias C-init pipeline registers
    f32x16 bA, bB;
    {
        int t0 = w * 512;
        int a0 = (7 - (t0 >> 8)) * 627 + (15 - ((t0 >> 4) & 15)) * 33 + lbase;
#pragma unroll
        for (int r = 0; r < 4; ++r) {
            bA[r] = smem[a0 + r];      bA[4 + r] = smem[a0 + 8 + r];
            bA[8 + r] = smem[a0 - 33 + r]; bA[12 + r] = smem[a0 - 25 + r];
            bB[r] = smem[a0 + 66 + r]; bB[4 + r] = smem[a0 + 74 + r];
            bB[8 + r] = smem[a0 + 33 + r]; bB[12 + r] = smem[a0 + 41 + r];
        }
    }

    // K-frag pipeline registers
    bf16x8 ck0, ck1;
    {
        const __bf16* kt = kbase + ((size_t)(w * 16) * 128 + lane) * 8;
        ck0 = *(const bf16x8*)(kt);
        ck1 = *(const bf16x8*)(kt + 512);
    }

#pragma unroll
    for (int it = 0; it < 16; ++it) {
        int t0 = w * 512 + it * 32;
        int tt = t0 >> 5;

        // prefetch next K frags
        bf16x8 nk0, nk1;
        if (it < 15) {
            const __bf16* kt1 = kbase + ((size_t)(tt + 1) * 128 + lane) * 8;
            nk0 = *(const bf16x8*)(kt1);
            nk1 = *(const bf16x8*)(kt1 + 512);
        }

        // V frags (contiguous), shared by both strips
        const __bf16* vt = vbase + ((size_t)tt * 256 + lane) * 4;
        uint2 va  = *(const uint2*)(vt);
        uint2 vbq = *(const uint2*)(vt + 256);
        uint2 vc  = *(const uint2*)(vt + 512);
        uint2 vd  = *(const uint2*)(vt + 768);
        uint32x4 vw0 = {va.x, va.y, vbq.x, vbq.y};
        uint32x4 vw1 = {vc.x, vc.y, vd.x, vd.y};
        bf16x8 vf0 = __builtin_bit_cast(bf16x8, vw0);
        bf16x8 vf1 = __builtin_bit_cast(bf16x8, vw1);

        // QK^T with prefetched bias C-init
        f32x16 SA = bA, SB = bB;
        SA = mfma32(ck0, qfA0, SA);
        SA = mfma32(ck1, qfA1, SA);
        SB = mfma32(ck0, qfB0, SB);
        SB = mfma32(ck1, qfB1, SB);

        // prefetch iter+1 bias (LDS latency hides under exp/pack/PV below)
        if (it < 15) {
            int t1 = t0 + 32;
            int a0 = (7 - (t1 >> 8)) * 627 + (15 - ((t1 >> 4) & 15)) * 33 + lbase;
#pragma unroll
            for (int r = 0; r < 4; ++r) {
                bA[r] = smem[a0 + r];      bA[4 + r] = smem[a0 + 8 + r];
                bA[8 + r] = smem[a0 - 33 + r]; bA[12 + r] = smem[a0 - 25 + r];
                bB[r] = smem[a0 + 66 + r]; bB[4 + r] = smem[a0 + 74 + r];
                bB[8 + r] = smem[a0 + 33 + r]; bB[12 + r] = smem[a0 + 41 + r];
            }
        }

        // strip A
        {
            unsigned W0 = pkbf16(fexp2(SA[0]),  fexp2(SA[1]));
            unsigned W1 = pkbf16(fexp2(SA[2]),  fexp2(SA[3]));
            unsigned W2 = pkbf16(fexp2(SA[4]),  fexp2(SA[5]));
            unsigned W3 = pkbf16(fexp2(SA[6]),  fexp2(SA[7]));
            unsigned W4 = pkbf16(fexp2(SA[8]),  fexp2(SA[9]));
            unsigned W5 = pkbf16(fexp2(SA[10]), fexp2(SA[11]));
            unsigned W6 = pkbf16(fexp2(SA[12]), fexp2(SA[13]));
            unsigned W7 = pkbf16(fexp2(SA[14]), fexp2(SA[15]));
            uint32x4 pw0 = {W0, W1, W2, W3};
            uint32x4 pw1 = {W4, W5, W6, W7};
            bf16x8 pf0 = __builtin_bit_cast(bf16x8, pw0);
            bf16x8 pf1 = __builtin_bit_cast(bf16x8, pw1);
            OaccA = mfma32(vf0, pf0, OaccA);
            OaccA = mfma32(vf1, pf1, OaccA);
            LaccA = mfma32(ones, pf0, LaccA);
            LaccA = mfma32(ones, pf1, LaccA);
        }
        // strip B
        {
            unsigned W0 = pkbf16(fexp2(SB[0]),  fexp2(SB[1]));
            unsigned W1 = pkbf16(fexp2(SB[2]),  fexp2(SB[3]));
            unsigned W2 = pkbf16(fexp2(SB[4]),  fexp2(SB[5]));
            unsigned W3 = pkbf16(fexp2(SB[6]),  fexp2(SB[7]));
            unsigned W4 = pkbf16(fexp2(SB[8]),  fexp2(SB[9]));
            unsigned W5 = pkbf16(fexp2(SB[10]), fexp2(SB[11]));
            unsigned W6 = pkbf16(fexp2(SB[12]), fexp2(SB[13]));
            unsigned W7 = pkbf16(fexp2(SB[14]), fexp2(SB[15]));
            uint32x4 pw0 = {W0, W1, W2, W3};
            uint32x4 pw1 = {W4, W5, W6, W7};
            bf16x8 pf0 = __builtin_bit_cast(bf16x8, pw0);
            bf16x8 pf1 = __builtin_bit_cast(bf16x8, pw1);
            OaccB = mfma32(vf0, pf0, OaccB);
            OaccB = mfma32(vf1, pf1, OaccB);
            LaccB = mfma32(ones, pf0, LaccB);
            LaccB = mfma32(ones, pf1, LaccB);
        }

        if (it < 15) { ck0 = nk0; ck1 = nk1; }
    }

    // ---- combine 4 k-partials via LDS (reuse smem as part[4][64][17]) ----
    float (*part)[64][17] = (float (*)[64][17])smem;
#pragma unroll
    for (int s = 0; s < 2; ++s) {
        f32x16* O = s ? &OaccB : &OaccA;
        f32x16* L = s ? &LaccB : &LaccA;
        __syncthreads();
#pragma unroll
        for (int j = 0; j < 4; ++j) {
            float4 t;
            t.x = (*O)[4 * j]; t.y = (*O)[4 * j + 1]; t.z = (*O)[4 * j + 2]; t.w = (*O)[4 * j + 3];
            *(float4*)&part[w][lane][4 * j] = t;
        }
        part[w][lane][16] = (*L)[0];
        __syncthreads();

        float4 o = {0.f, 0.f, 0.f, 0.f};
        float ls = 0.f;
#pragma unroll
        for (int sw = 0; sw < 4; ++sw) {
            float4 t = *(const float4*)&part[sw][lane][4 * w];
            o.x += t.x; o.y += t.y; o.z += t.z; o.w += t.w;
            ls += part[sw][lane][16];
        }
        float inv = 1.0f / ls;
        unsigned lo = pkbf16(o.x * inv, o.y * inv);
        unsigned hi = pkbf16(o.z * inv, o.w * inv);
        size_t base = ((size_t)b_ * NTOK + q0 + 32 * s + lq) * 256 + h * 32 + 8 * w + 4 * hf;
        *(uint2*)(attn + base) = make_uint2(lo, hi);
    }
}

// ---------------- kernel 3: output projection -> fp32, 32x64 tile per wave ------
__global__ __launch_bounds__(256) void k_out(const __bf16* __restrict__ attn,
                                             const __bf16* __restrict__ woT,
                                             float* __restrict__ out) {
    int wid = blockIdx.x * 4 + (threadIdx.x >> 6);   // 0..1023
    int lane = threadIdx.x & 63;
    int ng = wid & 3, mt = wid >> 2;                 // mt 0..255 (32-row strips)
    int lm = lane & 15, lg = lane >> 4, lk = lg * 8;
    int nc0 = ng * 64;

    f32x4 acc[2][4];
#pragma unroll
    for (int m = 0; m < 2; ++m)
#pragma unroll
        for (int n = 0; n < 4; ++n) acc[m][n] = (f32x4){0.f, 0.f, 0.f, 0.f};

    const __bf16* arow = attn + (size_t)(mt * 32 + lm) * 256 + lk;
    const __bf16* brow = woT + (size_t)(nc0 + lm) * 256 + lk;
#pragma unroll
    for (int kk = 0; kk < 8; ++kk) {
        bf16x8 a[2], b[4];
#pragma unroll
        for (int m = 0; m < 2; ++m) a[m] = *(const bf16x8*)(arow + (size_t)m * 16 * 256 + kk * 32);
#pragma unroll
        for (int n = 0; n < 4; ++n) b[n] = *(const bf16x8*)(brow + (size_t)n * 16 * 256 + kk * 32);
#pragma unroll
        for (int m = 0; m < 2; ++m)
#pragma unroll
            for (int n = 0; n < 4; ++n) acc[m][n] = mfma16(a[m], b[n], acc[m][n]);
    }
#pragma unroll
    for (int m = 0; m < 2; ++m) {
#pragma unroll
        for (int n = 0; n < 4; ++n) {
            int col = nc0 + n * 16 + lm;
#pragma unroll
            for (int r = 0; r < 4; ++r) {
                int row = mt * 32 + m * 16 + lg * 4 + r;
                out[(size_t)row * 256 + col] = acc[m][n][r];
            }
        }
    }
}

extern "C" void kernel_launch(void* const* d_in, const int* in_sizes, int n_in,
                              void* d_out, int out_size, void* d_ws, size_t ws_size,
                              hipStream_t stream) {
    const float* x    = (const float*)d_in[0];
    const float* Wq   = (const float*)d_in[1];
    const float* Wk   = (const float*)d_in[2];
    const float* Wv   = (const float*)d_in[3];
    const float* Wo   = (const float*)d_in[4];
    const float* bias = (const float*)d_in[5];
    float* out = (float*)d_out;

    __bf16* ws  = (__bf16*)d_ws;
    __bf16* xb  = ws;                       // 2,097,152 bf16 (reused as att)
    __bf16* wqT = xb  + 2097152;
    __bf16* wkT = wqT + 65536;
    __bf16* wvT = wkT + 65536;
    __bf16* woT = wvT + 65536;
    __bf16* qb  = woT + 65536;              // (b,h,n,32)
    __bf16* kb  = qb  + 2097152;            // (b,h) fragment-major K tiles
    __bf16* vb  = kb  + 2097152;            // (b,h) fragment-major V tiles
    __bf16* att = xb;                       // alias: xb dead after k_qkv

    k_prep<<<3072, 256, 0, stream>>>(x, Wq, Wk, Wv, Wo, xb, wqT, wkT, wvT, woT);
    k_qkv<<<1536, 64, 0, stream>>>(xb, wqT, wkT, wvT, qb, kb, vb);
    k_attn<<<1024, 256, 0, stream>>>(qb, kb, vb, bias, att);
    k_out<<<256, 256, 0, stream>>>(att, woT, out);
}